// Round 1
// baseline (1703.120 us; speedup 1.0000x reference)
//
#include <hip/hip_runtime.h>
#include <math.h>

#define N1 16384
#define N2 4096
#define DIM 256
#define ATT 128

// ---- workspace layout (float offsets), total ~8.4 MB ----
#define WS_KP      0            // K = x2@wk   [N2*DIM]
#define WS_VP      1048576      // V = x2@wv   [N2*DIM]
#define WS_ACC     2097152      // zeroed accumulators: 1024 floats
#define WS_COLSUM1 (WS_ACC + 0)     // [256]
#define WS_COLSUM2 (WS_ACC + 256)   // [256]
#define WS_S2SUM   (WS_ACC + 512)   // [256]
#define WS_POOLED  (WS_ACC + 768)   // [256]
#define WS_ALOGIT  (WS_ACC + 1024)  // [4096]
#define WS_AW      (WS_ALOGIT + 4096) // [4096]
#define WS_CVEC    (WS_AW + 4096)     // [256]
#define WS_GATE    (WS_CVEC + 256)    // [8]: w0,w1,w2,w3,inv_ns,cx1

// ---------------- column sums of x1 (for gate mean) ----------------
__global__ __launch_bounds__(256) void k_colsum1(const float* __restrict__ x1,
                                                 float* __restrict__ ws)
{
    const int t = threadIdx.x;
    const int rbase = blockIdx.x * 256;
    float acc = 0.f;
    for (int r = 0; r < 256; ++r) acc += x1[(rbase + r) * DIM + t];
    atomicAdd(&ws[WS_COLSUM1 + t], acc);
}

// ---------------- x2 prep: K, V, SNN-pool, DAMISL logits, colsum2 ----------------
__global__ __launch_bounds__(256) void k_x2prep(const float* __restrict__ x2,
    const float* __restrict__ wk, const float* __restrict__ wv,
    const float* __restrict__ snn_w2, const float* __restrict__ g2,
    const float* __restrict__ b2,
    const float* __restrict__ va, const float* __restrict__ ua,
    const float* __restrict__ wa,
    float* __restrict__ ws)
{
    __shared__ float xs[8][260];
    __shared__ float rr[8];
    __shared__ float hbuf[2][8][132];
    __shared__ float red2[8][2];
    const int t = threadIdx.x;
    const int base = blockIdx.x * 8 * DIM;

    for (int i = t; i < 8 * DIM; i += 256) xs[i >> 8][i & 255] = x2[base + i];
    __syncthreads();

    { // column partial sums
        float s = 0.f;
        #pragma unroll
        for (int r = 0; r < 8; ++r) s += xs[r][t];
        atomicAdd(&ws[WS_COLSUM2 + t], s);
    }
    { // rms factors, 32 threads per row
        const int row = t >> 5, l32 = t & 31;
        float p = 0.f;
        #pragma unroll
        for (int j = 0; j < 8; ++j) { const float v = xs[row][l32 + 32 * j]; p += v * v; }
        #pragma unroll
        for (int off = 16; off > 0; off >>= 1) p += __shfl_down(p, off, 32);
        if (l32 == 0) rr[row] = rsqrtf(p * (1.0f / DIM) + 1e-6f);
    }
    __syncthreads();

    { // K, V, SNN matmuls; thread t = output column
        float accK[8], accV[8], accS[8];
        #pragma unroll
        for (int r = 0; r < 8; ++r) { accK[r] = 0.f; accV[r] = 0.f; accS[r] = 0.f; }
        for (int k4 = 0; k4 < 64; ++k4) {
            float xk[8][4];
            #pragma unroll
            for (int r = 0; r < 8; ++r) {
                const float4 v = *(const float4*)&xs[r][k4 * 4];
                xk[r][0] = v.x; xk[r][1] = v.y; xk[r][2] = v.z; xk[r][3] = v.w;
            }
            #pragma unroll
            for (int i = 0; i < 4; ++i) {
                const int k = k4 * 4 + i;
                const float wkv = wk[k * DIM + t];
                const float wvv = wv[k * DIM + t];
                const float wsv = g2[k] * snn_w2[k * DIM + t];
                #pragma unroll
                for (int r = 0; r < 8; ++r) {
                    accK[r] = fmaf(xk[r][i], wkv, accK[r]);
                    accV[r] = fmaf(xk[r][i], wvv, accV[r]);
                    accS[r] = fmaf(xk[r][i], wsv, accS[r]);
                }
            }
        }
        const float b2v = b2[t];
        float ssum = 0.f;
        #pragma unroll
        for (int r = 0; r < 8; ++r) {
            ws[WS_KP + base + r * DIM + t] = accK[r];
            ws[WS_VP + base + r * DIM + t] = accV[r];
            const float ev = accS[r] * rr[r] + b2v;
            ssum += (ev > 0.f) ? ev : expm1f(ev);
        }
        atomicAdd(&ws[WS_S2SUM + t], ssum);
    }

    { // DAMISL gated-attention logits: half threads va, half ua
        const int j = t & 127;
        const int half = t >> 7;
        const float* __restrict__ W = half ? ua : va;
        float acc8[8];
        #pragma unroll
        for (int r = 0; r < 8; ++r) acc8[r] = 0.f;
        for (int k4 = 0; k4 < 64; ++k4) {
            float xk[8][4];
            #pragma unroll
            for (int r = 0; r < 8; ++r) {
                const float4 v = *(const float4*)&xs[r][k4 * 4];
                xk[r][0] = v.x; xk[r][1] = v.y; xk[r][2] = v.z; xk[r][3] = v.w;
            }
            #pragma unroll
            for (int i = 0; i < 4; ++i) {
                const float wv_ = W[(k4 * 4 + i) * ATT + j];
                #pragma unroll
                for (int r = 0; r < 8; ++r) acc8[r] = fmaf(xk[r][i], wv_, acc8[r]);
            }
        }
        #pragma unroll
        for (int r = 0; r < 8; ++r) hbuf[half][r][j] = acc8[r];
    }
    __syncthreads();
    if (t < 128) {
        const float waj = wa[t];
        #pragma unroll
        for (int r = 0; r < 8; ++r) {
            const float hv = hbuf[0][r][t];
            const float hu = hbuf[1][r][t];
            float p = tanhf(hv) * (1.0f / (1.0f + expf(-hu))) * waj;
            #pragma unroll
            for (int off = 32; off > 0; off >>= 1) p += __shfl_down(p, off, 64);
            if ((t & 63) == 0) red2[r][t >> 6] = p;
        }
    }
    __syncthreads();
    if (t < 8) ws[WS_ALOGIT + blockIdx.x * 8 + t] = red2[t][0] + red2[t][1];
}

// ---------------- block reduction helpers ----------------
__device__ __forceinline__ float block_sum256(float v, float* red, int t)
{
    red[t] = v; __syncthreads();
    for (int s = 128; s > 0; s >>= 1) {
        if (t < s) red[t] += red[t + s];
        __syncthreads();
    }
    const float r = red[0];
    __syncthreads();
    return r;
}
__device__ __forceinline__ float block_max256(float v, float* red, int t)
{
    red[t] = v; __syncthreads();
    for (int s = 128; s > 0; s >>= 1) {
        if (t < s) red[t] = fmaxf(red[t], red[t + s]);
        __syncthreads();
    }
    const float r = red[0];
    __syncthreads();
    return r;
}

// ---------------- gate (cosine top-2) + DAMISL softmax ----------------
__global__ __launch_bounds__(256) void k_gate(const float* __restrict__ sim,
    const float* __restrict__ gates, float* __restrict__ ws)
{
    __shared__ float red[256];
    __shared__ float sc[4];
    const int t = threadIdx.x;
    const float f = 0.5f * (ws[WS_COLSUM1 + t] * (1.0f / N1) +
                            ws[WS_COLSUM2 + t] * (1.0f / N2));
    const float fs = block_sum256(f * f, red, t);
    const float rsqf = rsqrtf(fs + 1e-8f);
    for (int e = 0; e < 4; ++e) {
        const float sv = sim[e * DIM + t];
        const float n2 = block_sum256(sv * sv, red, t);
        const float dt = block_sum256(sv * f, red, t);
        if (t == 0) sc[e] = dt * rsqf * rsqrtf(n2 + 1e-8f);
    }
    __syncthreads();
    if (t == 0) {
        float a = -1e30f, b = -1e30f;
        #pragma unroll
        for (int e = 0; e < 4; ++e) {
            const float v = sc[e];
            if (v > a) { b = a; a = v; } else if (v > b) { b = v; }
        }
        float w[4]; int ns = 0;
        #pragma unroll
        for (int e = 0; e < 4; ++e) {
            const bool keep = (sc[e] >= b) && (sc[e] > gates[e]);
            w[e] = keep ? sc[e] : 0.f;
            if (w[e] > 0.f) ns++;
        }
        if (ns < 1) ns = 1;
        ws[WS_GATE + 0] = w[0]; ws[WS_GATE + 1] = w[1];
        ws[WS_GATE + 2] = w[2]; ws[WS_GATE + 3] = w[3];
        ws[WS_GATE + 4] = 1.0f / (float)ns;
        ws[WS_GATE + 5] = w[0] + w[2] + w[3];   // coefficient of x1 in combine
    }
    __syncthreads();
    // softmax over DAMISL logits [4096]
    float mx = -1e30f;
    for (int i = t; i < N2; i += 256) mx = fmaxf(mx, ws[WS_ALOGIT + i]);
    mx = block_max256(mx, red, t);
    float sm = 0.f;
    for (int i = t; i < N2; i += 256) {
        const float e_ = expf(ws[WS_ALOGIT + i] - mx);
        ws[WS_AW + i] = e_;
        sm += e_;
    }
    sm = block_sum256(sm, red, t);
    const float is = 1.0f / sm;
    for (int i = t; i < N2; i += 256) ws[WS_AW + i] *= is;
}

// ---------------- pooled = a^T x2 ----------------
__global__ __launch_bounds__(256) void k_pooled(const float* __restrict__ x2,
                                                float* __restrict__ ws)
{
    const int t = threadIdx.x;
    const int rbase = blockIdx.x * 256;
    float acc = 0.f;
    for (int r = 0; r < 256; ++r)
        acc = fmaf(ws[WS_AW + rbase + r], x2[(rbase + r) * DIM + t], acc);
    atomicAdd(&ws[WS_POOLED + t], acc);
}

// ---------------- cvec = w1*s2mean + w2*(pooled@wf) ----------------
__global__ __launch_bounds__(256) void k_cvec(const float* __restrict__ wf,
                                              float* __restrict__ ws)
{
    __shared__ float pl[256];
    const int t = threadIdx.x;
    pl[t] = ws[WS_POOLED + t];
    __syncthreads();
    float acc = 0.f;
    for (int k = 0; k < 256; ++k) acc = fmaf(pl[k], wf[k * DIM + t], acc);
    const float w1 = ws[WS_GATE + 1], w2 = ws[WS_GATE + 2];
    ws[WS_CVEC + t] = w1 * (ws[WS_S2SUM + t] * (1.0f / N2)) + w2 * acc;
}

// ---------------- flash attention + fused epilogue (writes d_out) ----------------
// TQ=32 queries/block, TK=32 keys/tile, shared K/V LDS buffer, max-free softmax.
__global__ __launch_bounds__(256) void k_flash(const float* __restrict__ x1,
    const float* __restrict__ wq, const float* __restrict__ wo,
    const float* __restrict__ snn_w1, const float* __restrict__ g1,
    const float* __restrict__ b1,
    const float* __restrict__ ws, float* __restrict__ out)
{
    __shared__ float Qs[32][260];   // Q tile; later reused for normalized O
    __shared__ float Ks[32][260];   // K tile / V tile / x1 tile (time-multiplexed)
    __shared__ float Ps[32][33];    // exp(S) tile
    __shared__ float lred[16][32];
    __shared__ float linv[32];
    __shared__ float rr[32];
    const int t = threadIdx.x;
    const int qb = blockIdx.x * 32;
    const int qa = t & 15;          // rows qa, qa+16 (phase B & D)
    const int ka = t >> 4;          // keys ka, ka+16 (phase B)
    const int dg = (t >> 4) * 16;   // dims dg..dg+15 (phase D)

    // ---- prologue: x1 tile -> Ks, Q tile = x1@wq -> Qs
    {
        const float4* Xg = (const float4*)x1 + qb * 64;
        for (int i = t; i < 2048; i += 256)
            *(float4*)&Ks[i >> 6][(i & 63) * 4] = Xg[i];
    }
    __syncthreads();
    {
        float accq[32];
        #pragma unroll
        for (int r = 0; r < 32; ++r) accq[r] = 0.f;
        for (int k4 = 0; k4 < 64; ++k4) {
            float wqv[4];
            #pragma unroll
            for (int i = 0; i < 4; ++i) wqv[i] = wq[(k4 * 4 + i) * DIM + t];
            #pragma unroll
            for (int r = 0; r < 32; ++r) {
                const float4 xv = *(const float4*)&Ks[r][k4 * 4];
                accq[r] = fmaf(xv.x, wqv[0], fmaf(xv.y, wqv[1],
                          fmaf(xv.z, wqv[2], fmaf(xv.w, wqv[3], accq[r]))));
            }
        }
        #pragma unroll
        for (int r = 0; r < 32; ++r) Qs[r][t] = accq[r];
    }
    __syncthreads();

    float Oa0[16], Oa1[16];
    #pragma unroll
    for (int i = 0; i < 16; ++i) { Oa0[i] = 0.f; Oa1[i] = 0.f; }
    float l0 = 0.f, l1 = 0.f;

    const float4* Kg = (const float4*)(ws + WS_KP);
    const float4* Vg = (const float4*)(ws + WS_VP);

    for (int tile = 0; tile < N2 / 32; ++tile) {
        for (int i = t; i < 2048; i += 256)
            *(float4*)&Ks[i >> 6][(i & 63) * 4] = Kg[tile * 2048 + i];
        __syncthreads();
        // phase B: S = Q.K^T / 16, 2q x 2k per thread
        float s00 = 0.f, s01 = 0.f, s10 = 0.f, s11 = 0.f;
        for (int k4 = 0; k4 < 64; ++k4) {
            const float4 q0 = *(const float4*)&Qs[qa][k4 * 4];
            const float4 q1 = *(const float4*)&Qs[qa + 16][k4 * 4];
            const float4 c0 = *(const float4*)&Ks[ka][k4 * 4];
            const float4 c1 = *(const float4*)&Ks[ka + 16][k4 * 4];
            s00 = fmaf(q0.x, c0.x, fmaf(q0.y, c0.y, fmaf(q0.z, c0.z, fmaf(q0.w, c0.w, s00))));
            s01 = fmaf(q0.x, c1.x, fmaf(q0.y, c1.y, fmaf(q0.z, c1.z, fmaf(q0.w, c1.w, s01))));
            s10 = fmaf(q1.x, c0.x, fmaf(q1.y, c0.y, fmaf(q1.z, c0.z, fmaf(q1.w, c0.w, s10))));
            s11 = fmaf(q1.x, c1.x, fmaf(q1.y, c1.y, fmaf(q1.z, c1.z, fmaf(q1.w, c1.w, s11))));
        }
        const float p00 = expf(s00 * 0.0625f);
        const float p01 = expf(s01 * 0.0625f);
        const float p10 = expf(s10 * 0.0625f);
        const float p11 = expf(s11 * 0.0625f);
        l0 += p00 + p01;
        l1 += p10 + p11;
        Ps[qa][ka] = p00;      Ps[qa][ka + 16] = p01;
        Ps[qa + 16][ka] = p10; Ps[qa + 16][ka + 16] = p11;
        __syncthreads();
        for (int i = t; i < 2048; i += 256)
            *(float4*)&Ks[i >> 6][(i & 63) * 4] = Vg[tile * 2048 + i];
        __syncthreads();
        // phase D: O += P.V, 2q x 16d per thread
        for (int kk = 0; kk < 32; ++kk) {
            const float pa = Ps[qa][kk];
            const float pb = Ps[qa + 16][kk];
            #pragma unroll
            for (int i4 = 0; i4 < 4; ++i4) {
                const float4 vv = *(const float4*)&Ks[kk][dg + i4 * 4];
                Oa0[i4 * 4 + 0] = fmaf(pa, vv.x, Oa0[i4 * 4 + 0]);
                Oa0[i4 * 4 + 1] = fmaf(pa, vv.y, Oa0[i4 * 4 + 1]);
                Oa0[i4 * 4 + 2] = fmaf(pa, vv.z, Oa0[i4 * 4 + 2]);
                Oa0[i4 * 4 + 3] = fmaf(pa, vv.w, Oa0[i4 * 4 + 3]);
                Oa1[i4 * 4 + 0] = fmaf(pb, vv.x, Oa1[i4 * 4 + 0]);
                Oa1[i4 * 4 + 1] = fmaf(pb, vv.y, Oa1[i4 * 4 + 1]);
                Oa1[i4 * 4 + 2] = fmaf(pb, vv.z, Oa1[i4 * 4 + 2]);
                Oa1[i4 * 4 + 3] = fmaf(pb, vv.w, Oa1[i4 * 4 + 3]);
            }
        }
        __syncthreads();
    }

    // ---- softmax denominators (one reduction at the end; max-free is safe here)
    lred[ka][qa] = l0;
    lred[ka][qa + 16] = l1;
    __syncthreads();
    if (t < 32) {
        float s = 0.f;
        #pragma unroll
        for (int m = 0; m < 16; ++m) s += lred[m][t];
        linv[t] = 1.0f / s;
    }
    __syncthreads();
    // normalized O -> Qs; reload x1 tile -> Ks
    {
        const float la = linv[qa], lb = linv[qa + 16];
        #pragma unroll
        for (int i = 0; i < 16; ++i) {
            Qs[qa][dg + i] = Oa0[i] * la;
            Qs[qa + 16][dg + i] = Oa1[i] * lb;
        }
    }
    {
        const float4* Xg = (const float4*)x1 + qb * 64;
        for (int i = t; i < 2048; i += 256)
            *(float4*)&Ks[i >> 6][(i & 63) * 4] = Xg[i];
    }
    __syncthreads();
    { // rms of x1 rows, 8 threads per row
        const int row = t >> 3, l8 = t & 7;
        float p = 0.f;
        #pragma unroll
        for (int j = 0; j < 32; ++j) { const float v = Ks[row][l8 + 8 * j]; p += v * v; }
        #pragma unroll
        for (int off = 4; off > 0; off >>= 1) p += __shfl_down(p, off, 8);
        if (l8 == 0) rr[row] = rsqrtf(p * (1.0f / DIM) + 1e-6f);
    }
    __syncthreads();
    // ---- epilogue: O@wo and rms(x1)@snn_w1, combine, write out
    {
        float acc_o[32], acc_s[32];
        #pragma unroll
        for (int r = 0; r < 32; ++r) { acc_o[r] = 0.f; acc_s[r] = 0.f; }
        for (int k4 = 0; k4 < 64; ++k4) {
            float wov[4], wsv[4];
            #pragma unroll
            for (int i = 0; i < 4; ++i) {
                const int k = k4 * 4 + i;
                wov[i] = wo[k * DIM + t];
                wsv[i] = g1[k] * snn_w1[k * DIM + t];
            }
            #pragma unroll
            for (int r = 0; r < 32; ++r) {
                const float4 ov = *(const float4*)&Qs[r][k4 * 4];
                const float4 xv = *(const float4*)&Ks[r][k4 * 4];
                acc_o[r] = fmaf(ov.x, wov[0], fmaf(ov.y, wov[1],
                           fmaf(ov.z, wov[2], fmaf(ov.w, wov[3], acc_o[r]))));
                acc_s[r] = fmaf(xv.x, wsv[0], fmaf(xv.y, wsv[1],
                           fmaf(xv.z, wsv[2], fmaf(xv.w, wsv[3], acc_s[r]))));
            }
        }
        const float b1v = b1[t];
        const float w0 = ws[WS_GATE + 0], w1 = ws[WS_GATE + 1];
        const float inv = ws[WS_GATE + 4], cx1 = ws[WS_GATE + 5];
        const float cv = ws[WS_CVEC + t];
        #pragma unroll
        for (int r = 0; r < 32; ++r) {
            const float ev = acc_s[r] * rr[r] + b1v;
            const float e1v = (ev > 0.f) ? ev : expm1f(ev);
            out[(qb + r) * DIM + t] = inv * (cx1 * Ks[r][t] + w0 * acc_o[r] + w1 * e1v + cv);
        }
    }
}

extern "C" void kernel_launch(void* const* d_in, const int* in_sizes, int n_in,
                              void* d_out, int out_size, void* d_ws, size_t ws_size,
                              hipStream_t stream)
{
    const float* x1    = (const float*)d_in[0];
    const float* x2    = (const float*)d_in[1];
    const float* sim   = (const float*)d_in[2];
    const float* gates = (const float*)d_in[3];
    const float* g1    = (const float*)d_in[4];
    const float* g2    = (const float*)d_in[5];
    const float* w1m   = (const float*)d_in[6];
    const float* b1    = (const float*)d_in[7];
    const float* w2m   = (const float*)d_in[8];
    const float* b2    = (const float*)d_in[9];
    const float* wq    = (const float*)d_in[10];
    const float* wk    = (const float*)d_in[11];
    const float* wv    = (const float*)d_in[12];
    const float* wo    = (const float*)d_in[13];
    const float* va    = (const float*)d_in[14];
    const float* ua    = (const float*)d_in[15];
    const float* wa    = (const float*)d_in[16];
    const float* wf    = (const float*)d_in[17];
    float* ws  = (float*)d_ws;
    float* out = (float*)d_out;

    hipMemsetAsync(ws + WS_ACC, 0, 1024 * sizeof(float), stream);
    hipLaunchKernelGGL(k_colsum1, dim3(N1 / 256), dim3(256), 0, stream, x1, ws);
    hipLaunchKernelGGL(k_x2prep, dim3(N2 / 8), dim3(256), 0, stream,
                       x2, wk, wv, w2m, g2, b2, va, ua, wa, ws);
    hipLaunchKernelGGL(k_gate, dim3(1), dim3(256), 0, stream, sim, gates, ws);
    hipLaunchKernelGGL(k_pooled, dim3(16), dim3(256), 0, stream, x2, ws);
    hipLaunchKernelGGL(k_cvec, dim3(1), dim3(256), 0, stream, wf, ws);
    hipLaunchKernelGGL(k_flash, dim3(N1 / 32), dim3(256), 0, stream,
                       x1, wq, wo, w1m, g1, b1, ws, out);
}

// Round 2
// 360.243 us; speedup vs baseline: 4.7277x; 4.7277x over previous
//
#include <hip/hip_runtime.h>
#include <math.h>

#define N1 16384
#define N2 4096
#define DIM 256
#define ATT 128

typedef unsigned int uint32;
typedef unsigned short ushort16;
typedef __attribute__((ext_vector_type(4))) short s4v;
typedef __attribute__((ext_vector_type(8))) short s8v;
typedef __attribute__((ext_vector_type(16))) float f16v;
typedef __attribute__((ext_vector_type(2))) uint32 u2v;
typedef __attribute__((ext_vector_type(4))) uint32 u4v;

union S8U { s8v v; s4v h[2]; };

#define AS1C const __attribute__((address_space(1)))
#define AS3 __attribute__((address_space(3)))

// ---- workspace layout (float offsets) ----
#define WS_KPK 0              // K frag-packed bf16  [4096*256] = 2MB
#define WS_VPK 524288         // V^T frag-packed bf16
#define WS_WQT 1048576        // wq^T A-frag packed bf16 (128KB)
#define WS_WOT 1081344
#define WS_W1T 1114112
#define WS_ACC 1146880        // zeroed: colsum1,colsum2,s2sum,pooled (1024 f)
#define WS_COLSUM1 (WS_ACC)
#define WS_COLSUM2 (WS_ACC+256)
#define WS_S2SUM  (WS_ACC+512)
#define WS_POOLED (WS_ACC+768)
#define WS_ALOGIT (WS_ACC+1024)     // [4096]
#define WS_AW     (WS_ALOGIT+4096)  // [4096]
#define WS_CVEC   (WS_AW+4096)      // [256]
#define WS_GATE   (WS_CVEC+256)     // [8]

// ---- flash LDS layout (bytes) ----
#define L_KV0 0
#define L_KV1 65536
#define L_P   131072
#define L_LP  139264
#define L_LINV 140288
#define L_RRS 140544
#define L_RR  140800
#define L_CV  141056
#define L_B1  142080
#define L_X1PK  65536     // prologue alias (Kbuf1)
#define L_QPAD  98304     // prologue alias (Vbuf1 + 512B of P)
#define L_OBUF  0         // epilogue alias (Kbuf0)
#define L_X1PK2 32768     // epilogue alias (Vbuf0)
#define SMEM_BYTES 143360

__device__ __forceinline__ uint32 f2bf1(float f) {
    uint32 u = __float_as_uint(f);
    return (u + 0x7fffu + ((u >> 16) & 1u)) >> 16;
}
__device__ __forceinline__ uint32 f2bf2(float lo, float hi) {
    return f2bf1(lo) | (f2bf1(hi) << 16);
}
#define MFMA32(a, b, c) __builtin_amdgcn_mfma_f32_32x32x16_bf16((a), (b), (c), 0, 0, 0)

// ---------------- column sums of x1 (gate mean) ----------------
__global__ __launch_bounds__(256) void k_colsum1(const float* __restrict__ x1,
                                                 float* __restrict__ ws)
{
    const int t = threadIdx.x;
    const int rbase = blockIdx.x * 256;
    float acc = 0.f;
    for (int r = 0; r < 256; ++r) acc += x1[(size_t)(rbase + r) * DIM + t];
    atomicAdd(&ws[WS_COLSUM1 + t], acc);
}

// ---------------- x2 prep: Kpk, Vpk, SNN-pool, DAMISL logits, colsum2 ----------------
__global__ __launch_bounds__(256) void k_x2prep(const float* __restrict__ x2,
    const float* __restrict__ wk, const float* __restrict__ wv,
    const float* __restrict__ snn_w2, const float* __restrict__ g2,
    const float* __restrict__ b2,
    const float* __restrict__ va, const float* __restrict__ ua,
    const float* __restrict__ wa,
    float* __restrict__ ws)
{
    __shared__ float xs[8][260];
    __shared__ float rr[8];
    __shared__ float hbuf[2][8][132];
    __shared__ float red2[8][2];
    const int t = threadIdx.x;
    const int base = blockIdx.x * 8 * DIM;
    unsigned short* kpk = (unsigned short*)(ws + WS_KPK);
    unsigned short* vpk = (unsigned short*)(ws + WS_VPK);

    for (int i = t; i < 8 * DIM; i += 256) xs[i >> 8][i & 255] = x2[base + i];
    __syncthreads();

    { // column partial sums
        float s = 0.f;
        #pragma unroll
        for (int r = 0; r < 8; ++r) s += xs[r][t];
        atomicAdd(&ws[WS_COLSUM2 + t], s);
    }
    { // rms factors
        const int row = t >> 5, l32 = t & 31;
        float p = 0.f;
        #pragma unroll
        for (int j = 0; j < 8; ++j) { const float v = xs[row][l32 + 32 * j]; p += v * v; }
        #pragma unroll
        for (int off = 16; off > 0; off >>= 1) p += __shfl_down(p, off, 32);
        if (l32 == 0) rr[row] = rsqrtf(p * (1.0f / DIM) + 1e-6f);
    }
    __syncthreads();

    { // K, V, SNN matmuls; thread t = output column d
        float accK[8], accV[8], accS[8];
        #pragma unroll
        for (int r = 0; r < 8; ++r) { accK[r] = 0.f; accV[r] = 0.f; accS[r] = 0.f; }
        for (int k4 = 0; k4 < 64; ++k4) {
            float xk[8][4];
            #pragma unroll
            for (int r = 0; r < 8; ++r) {
                const float4 v = *(const float4*)&xs[r][k4 * 4];
                xk[r][0] = v.x; xk[r][1] = v.y; xk[r][2] = v.z; xk[r][3] = v.w;
            }
            #pragma unroll
            for (int i = 0; i < 4; ++i) {
                const int k = k4 * 4 + i;
                const float wkv = wk[k * DIM + t];
                const float wvv = wv[k * DIM + t];
                const float wsv = g2[k] * snn_w2[k * DIM + t];
                #pragma unroll
                for (int r = 0; r < 8; ++r) {
                    accK[r] = fmaf(xk[r][i], wkv, accK[r]);
                    accV[r] = fmaf(xk[r][i], wvv, accV[r]);
                    accS[r] = fmaf(xk[r][i], wsv, accS[r]);
                }
            }
        }
        const float b2v = b2[t];
        const int d = t;
        float ssum = 0.f;
        #pragma unroll
        for (int r = 0; r < 8; ++r) {
            const int key = blockIdx.x * 8 + r;
            // Kpk: tile-chunk = 2*(d>>4) + kh ; lane = (key&31)+32*((d>>3)&1) ; j = d&7
            unsigned int offK = (unsigned int)((key >> 6) * 32 + 2 * (d >> 4) + ((key >> 5) & 1)) * 512u
                              + (unsigned int)((key & 31) + 32 * ((d >> 3) & 1)) * 8u + (d & 7);
            kpk[offK] = (unsigned short)f2bf1(accK[r]);
            // Vpk: chunk = 4*(d>>5) + ((key>>4)&3) ; lane = (d&31)+32*((key>>3)&1) ; j = key&7
            unsigned int offV = (unsigned int)((key >> 6) * 32 + 4 * (d >> 5) + ((key >> 4) & 3)) * 512u
                              + (unsigned int)((d & 31) + 32 * ((key >> 3) & 1)) * 8u + (key & 7);
            vpk[offV] = (unsigned short)f2bf1(accV[r]);
            const float ev = accS[r] * rr[r] + b2v;
            ssum += (ev > 0.f) ? ev : expm1f(ev);
        }
        atomicAdd(&ws[WS_S2SUM + t], ssum);
    }

    { // DAMISL gated-attention logits
        const int j = t & 127;
        const int half = t >> 7;
        const float* __restrict__ W = half ? ua : va;
        float acc8[8];
        #pragma unroll
        for (int r = 0; r < 8; ++r) acc8[r] = 0.f;
        for (int k4 = 0; k4 < 64; ++k4) {
            float xk[8][4];
            #pragma unroll
            for (int r = 0; r < 8; ++r) {
                const float4 v = *(const float4*)&xs[r][k4 * 4];
                xk[r][0] = v.x; xk[r][1] = v.y; xk[r][2] = v.z; xk[r][3] = v.w;
            }
            #pragma unroll
            for (int i = 0; i < 4; ++i) {
                const float wv_ = W[(k4 * 4 + i) * ATT + j];
                #pragma unroll
                for (int r = 0; r < 8; ++r) acc8[r] = fmaf(xk[r][i], wv_, acc8[r]);
            }
        }
        #pragma unroll
        for (int r = 0; r < 8; ++r) hbuf[half][r][j] = acc8[r];
    }
    __syncthreads();
    if (t < 128) {
        const float waj = wa[t];
        #pragma unroll
        for (int r = 0; r < 8; ++r) {
            const float hv = hbuf[0][r][t];
            const float hu = hbuf[1][r][t];
            float p = tanhf(hv) * (1.0f / (1.0f + expf(-hu))) * waj;
            #pragma unroll
            for (int off = 32; off > 0; off >>= 1) p += __shfl_down(p, off, 64);
            if ((t & 63) == 0) red2[r][t >> 6] = p;
        }
    }
    __syncthreads();
    if (t < 8) ws[WS_ALOGIT + blockIdx.x * 8 + t] = red2[t][0] + red2[t][1];
}

// ---------------- weight packing: wq^T / wo^T / (g1*snn_w1)^T frags ----------------
__global__ __launch_bounds__(256) void k_wpack(const float* __restrict__ wq,
    const float* __restrict__ wo, const float* __restrict__ snn_w1,
    const float* __restrict__ g1, float* __restrict__ ws)
{
    const int b = blockIdx.x;
    const int mat = b >> 5, chunk = b & 31;
    const int t = threadIdx.x;
    const float* W = (mat == 0) ? wq : (mat == 1) ? wo : snn_w1;
    unsigned short* dst = (unsigned short*)(ws + ((mat == 0) ? WS_WQT : (mat == 1) ? WS_WOT : WS_W1T));
    const int e0 = chunk * 2048 + t * 8;
    const int k = e0 >> 8, n0 = e0 & 255;
    const float4 v0 = *(const float4*)(W + k * 256 + n0);
    const float4 v1 = *(const float4*)(W + k * 256 + n0 + 4);
    const float sc = (mat == 2) ? g1[k] : 1.0f;
    float vals[8] = {v0.x, v0.y, v0.z, v0.w, v1.x, v1.y, v1.z, v1.w};
    const unsigned int sbase = (unsigned int)(k >> 4) * 512u + 32u * ((k >> 3) & 1) * 8u + (k & 7);
    #pragma unroll
    for (int jj = 0; jj < 8; ++jj) {
        const int n = n0 + jj;
        unsigned int off = (unsigned int)(n >> 5) * 16u * 512u + sbase + (unsigned int)(n & 31) * 8u;
        dst[off] = (unsigned short)f2bf1(vals[jj] * sc);
    }
}

// ---------------- block reductions ----------------
__device__ __forceinline__ float block_sum256(float v, float* red, int t)
{
    red[t] = v; __syncthreads();
    for (int s = 128; s > 0; s >>= 1) { if (t < s) red[t] += red[t + s]; __syncthreads(); }
    const float r = red[0]; __syncthreads(); return r;
}
__device__ __forceinline__ float block_max256(float v, float* red, int t)
{
    red[t] = v; __syncthreads();
    for (int s = 128; s > 0; s >>= 1) { if (t < s) red[t] = fmaxf(red[t], red[t + s]); __syncthreads(); }
    const float r = red[0]; __syncthreads(); return r;
}

// ---------------- gate (cosine top-2) + DAMISL softmax ----------------
__global__ __launch_bounds__(256) void k_gate(const float* __restrict__ sim,
    const float* __restrict__ gates, float* __restrict__ ws)
{
    __shared__ float red[256];
    __shared__ float sc[4];
    const int t = threadIdx.x;
    const float f = 0.5f * (ws[WS_COLSUM1 + t] * (1.0f / N1) +
                            ws[WS_COLSUM2 + t] * (1.0f / N2));
    const float fs = block_sum256(f * f, red, t);
    const float rsqf = rsqrtf(fs + 1e-8f);
    for (int e = 0; e < 4; ++e) {
        const float sv = sim[e * DIM + t];
        const float n2 = block_sum256(sv * sv, red, t);
        const float dt = block_sum256(sv * f, red, t);
        if (t == 0) sc[e] = dt * rsqf * rsqrtf(n2 + 1e-8f);
    }
    __syncthreads();
    if (t == 0) {
        float a = -1e30f, b = -1e30f;
        #pragma unroll
        for (int e = 0; e < 4; ++e) {
            const float v = sc[e];
            if (v > a) { b = a; a = v; } else if (v > b) { b = v; }
        }
        float w[4]; int ns = 0;
        #pragma unroll
        for (int e = 0; e < 4; ++e) {
            const bool keep = (sc[e] >= b) && (sc[e] > gates[e]);
            w[e] = keep ? sc[e] : 0.f;
            if (w[e] > 0.f) ns++;
        }
        if (ns < 1) ns = 1;
        ws[WS_GATE + 0] = w[0]; ws[WS_GATE + 1] = w[1];
        ws[WS_GATE + 2] = w[2]; ws[WS_GATE + 3] = w[3];
        ws[WS_GATE + 4] = 1.0f / (float)ns;
        ws[WS_GATE + 5] = w[0] + w[2] + w[3];
    }
    __syncthreads();
    float mx = -1e30f;
    for (int i = t; i < N2; i += 256) mx = fmaxf(mx, ws[WS_ALOGIT + i]);
    mx = block_max256(mx, red, t);
    float sm = 0.f;
    for (int i = t; i < N2; i += 256) {
        const float e_ = expf(ws[WS_ALOGIT + i] - mx);
        ws[WS_AW + i] = e_;
        sm += e_;
    }
    sm = block_sum256(sm, red, t);
    const float is = 1.0f / sm;
    for (int i = t; i < N2; i += 256) ws[WS_AW + i] *= is;
}

// ---------------- pooled = a^T x2 ----------------
__global__ __launch_bounds__(256) void k_pooled(const float* __restrict__ x2,
                                                float* __restrict__ ws)
{
    const int t = threadIdx.x;
    const int rbase = blockIdx.x * 256;
    float acc = 0.f;
    for (int r = 0; r < 256; ++r)
        acc = fmaf(ws[WS_AW + rbase + r], x2[(size_t)(rbase + r) * DIM + t], acc);
    atomicAdd(&ws[WS_POOLED + t], acc);
}

// ---------------- cvec = w1*s2mean + w2*(pooled@wf) ----------------
__global__ __launch_bounds__(256) void k_cvec(const float* __restrict__ wf,
                                              float* __restrict__ ws)
{
    __shared__ float pl[256];
    const int t = threadIdx.x;
    pl[t] = ws[WS_POOLED + t];
    __syncthreads();
    float acc = 0.f;
    for (int k = 0; k < 256; ++k) acc = fmaf(pl[k], wf[k * DIM + t], acc);
    const float w1 = ws[WS_GATE + 1], w2 = ws[WS_GATE + 2];
    ws[WS_CVEC + t] = w1 * (ws[WS_S2SUM + t] * (1.0f / N2)) + w2 * acc;
}

// ---------------- MFMA flash attention + fused epilogue ----------------
__global__ __launch_bounds__(256, 1) void k_flash(
    const float* __restrict__ x1, const float* __restrict__ b1,
    const float* __restrict__ wsf, float* __restrict__ out)
{
    extern __shared__ char sm[];
    const int t = threadIdx.x;
    const int w = t >> 6;
    const int lane = t & 63;
    const int l31 = lane & 31;
    const int lh = lane >> 5;
    const int qb = blockIdx.x * 64;
    const char* wsb = (const char*)wsf;
    const char* kpk = wsb + (size_t)WS_KPK * 4;
    const char* vpk = wsb + (size_t)WS_VPK * 4;
    const char* wqt = wsb + (size_t)WS_WQT * 4;
    const char* wot = wsb + (size_t)WS_WOT * 4;
    const char* w1t = wsb + (size_t)WS_W1T * 4;

    auto stage = [&](const char* gbase, int ldsoff) {
        #pragma unroll
        for (int i = 0; i < 8; ++i) {
            const int c = w + 4 * i;
            __builtin_amdgcn_global_load_lds(
                (AS1C uint32*)(gbase + c * 1024 + lane * 16),
                (AS3 uint32*)(sm + ldsoff + c * 1024), 16, 0, 0);
        }
    };

    // stage tile 0 into buf0
    stage(kpk, L_KV0);
    stage(vpk, L_KV0 + 32768);

    if (t < 64) {
        *(float4*)(sm + L_B1 + t * 16) = *(const float4*)(b1 + t * 4);
        *(float4*)(sm + L_CV + t * 16) = *(const float4*)(wsf + WS_CVEC + t * 4);
    }

    // ---- prologue: x1pk frags + rms sums
    #pragma unroll
    for (int i = 0; i < 8; ++i) {
        const int c = t + 256 * i;
        const int q = c >> 5, d0 = (c & 31) * 8;
        const float4 a = *(const float4*)(x1 + (size_t)(qb + q) * DIM + d0);
        const float4 b = *(const float4*)(x1 + (size_t)(qb + q) * DIM + d0 + 4);
        float ss = a.x*a.x + a.y*a.y + a.z*a.z + a.w*a.w
                 + b.x*b.x + b.y*b.y + b.z*b.z + b.w*b.w;
        #pragma unroll
        for (int o = 16; o > 0; o >>= 1) ss += __shfl_down(ss, o, 32);
        if ((t & 31) == 0) *(float*)(sm + L_RRS + q * 4) = ss;
        u4v pk;
        pk.x = f2bf2(a.x, a.y); pk.y = f2bf2(a.z, a.w);
        pk.z = f2bf2(b.x, b.y); pk.w = f2bf2(b.z, b.w);
        *(u4v*)(sm + L_X1PK + ((q >> 5) * 16 + (d0 >> 4)) * 1024
                + ((q & 31) + 32 * ((d0 >> 3) & 1)) * 16) = pk;
    }
    __syncthreads();
    if (t < 64) {
        const float s2 = *(const float*)(sm + L_RRS + t * 4);
        *(float*)(sm + L_RR + t * 4) = rsqrtf(s2 * (1.0f / DIM) + 1e-6f);
    }
    // ---- Q^T = wq^T * x1^T  (C/D: col=q, row=out-dim) -> Qpad [q][d] bf16
    #pragma unroll
    for (int i = 0; i < 2; ++i) {
        const int mt = 2 * w + i;
        f16v qa0 = (f16v)0.0f, qa1 = (f16v)0.0f;
        #pragma unroll
        for (int s = 0; s < 16; ++s) {
            const s8v a  = *(const s8v*)(wqt + (mt * 16 + s) * 1024 + lane * 16);
            const s8v b0 = *(const s8v*)(sm + L_X1PK + s * 1024 + lane * 16);
            const s8v b1f = *(const s8v*)(sm + L_X1PK + (16 + s) * 1024 + lane * 16);
            qa0 = MFMA32(a, b0, qa0);
            qa1 = MFMA32(a, b1f, qa1);
        }
        #pragma unroll
        for (int nt = 0; nt < 2; ++nt) {
            const f16v acc = nt ? qa1 : qa0;
            const int q = 32 * nt + l31;
            #pragma unroll
            for (int g = 0; g < 4; ++g) {
                const int d0 = 32 * mt + 8 * g + 4 * lh;
                u2v pk;
                pk.x = f2bf2(acc[4 * g + 0], acc[4 * g + 1]);
                pk.y = f2bf2(acc[4 * g + 2], acc[4 * g + 3]);
                *(u2v*)(sm + L_QPAD + q * 520 + d0 * 2) = pk;
            }
        }
    }
    __syncthreads();
    // ---- load Q B-frags into regs
    const int kh = w & 1, qh = w >> 1;
    s8v qf[16];
    {
        const char* qbase = sm + L_QPAD + (32 * qh + l31) * 520 + lh * 16;
        #pragma unroll
        for (int s = 0; s < 16; ++s) {
            S8U u;
            u.h[0] = *(const s4v*)(qbase + s * 32);
            u.h[1] = *(const s4v*)(qbase + s * 32 + 8);
            qf[s] = u.v;
        }
    }

    f16v oacc[4];
    #pragma unroll
    for (int i = 0; i < 4; ++i) oacc[i] = (f16v)0.0f;
    float lsum = 0.0f;
    __syncthreads();   // tile0 staged; Qpad reads complete

    // ---- main loop over 64 key-tiles
    for (int tile = 0; tile < 64; ++tile) {
        const int p = tile & 1;
        const int bo = p ? L_KV1 : L_KV0;
        const int bn = p ? L_KV0 : L_KV1;
        if (tile < 63) stage(kpk + (size_t)(tile + 1) * 32768, bn);
        // S^T = K * Q^T
        f16v sacc = (f16v)0.0f;
        #pragma unroll
        for (int s = 0; s < 16; ++s) {
            const s8v a = *(const s8v*)(sm + bo + (2 * s + kh) * 1024 + lane * 16);
            sacc = MFMA32(a, qf[s], sacc);
        }
        // exp (max-free), accumulate l, pack P -> LDS frags
        #pragma unroll
        for (int g = 0; g < 4; ++g) {
            const float p0 = expf(sacc[4 * g + 0] * 0.0625f);
            const float p1 = expf(sacc[4 * g + 1] * 0.0625f);
            const float p2 = expf(sacc[4 * g + 2] * 0.0625f);
            const float p3 = expf(sacc[4 * g + 3] * 0.0625f);
            lsum += (p0 + p1) + (p2 + p3);
            const int key0 = 8 * g + 4 * lh;
            const int sidx = 2 * kh + (key0 >> 4);
            const int koff = key0 & 15;
            const int dl = l31 + 32 * (koff >> 3);
            u2v pk; pk.x = f2bf2(p0, p1); pk.y = f2bf2(p2, p3);
            *(u2v*)(sm + L_P + (qh * 4 + sidx) * 1024 + dl * 16 + (koff & 7) * 2) = pk;
        }
        __syncthreads();
        if (tile < 63) stage(vpk + (size_t)(tile + 1) * 32768, bn + 32768);
        // O^T += V^T * P^T
        s8v pf[2][4];
        #pragma unroll
        for (int nt = 0; nt < 2; ++nt)
            #pragma unroll
            for (int s = 0; s < 4; ++s)
                pf[nt][s] = *(const s8v*)(sm + L_P + (nt * 4 + s) * 1024 + lane * 16);
        #pragma unroll
        for (int i = 0; i < 2; ++i) {
            const int mt = 2 * w + i;
            #pragma unroll
            for (int s = 0; s < 4; ++s) {
                const s8v a = *(const s8v*)(sm + bo + 32768 + (mt * 4 + s) * 1024 + lane * 16);
                oacc[2 * i + 0] = MFMA32(a, pf[0][s], oacc[2 * i + 0]);
                oacc[2 * i + 1] = MFMA32(a, pf[1][s], oacc[2 * i + 1]);
            }
        }
        __syncthreads();
    }

    // ---- softmax denominators
    *(float*)(sm + L_LP + ((w * 2 + lh) * 32 + l31) * 4) = lsum;
    __syncthreads();
    if (t < 64) {
        const int qh_ = t >> 5, c = t & 31;
        const float* lp = (const float*)(sm + L_LP);
        const float l = lp[((2 * qh_ + 0) * 2 + 0) * 32 + c] + lp[((2 * qh_ + 0) * 2 + 1) * 32 + c]
                      + lp[((2 * qh_ + 1) * 2 + 0) * 32 + c] + lp[((2 * qh_ + 1) * 2 + 1) * 32 + c];
        *(float*)(sm + L_LINV + t * 4) = 1.0f / l;
    }
    __syncthreads();
    // ---- pack Ohat = O/l into OBUF frags
    {
        float li[2];
        li[0] = *(const float*)(sm + L_LINV + l31 * 4);
        li[1] = *(const float*)(sm + L_LINV + (32 + l31) * 4);
        #pragma unroll
        for (int i = 0; i < 2; ++i) {
            const int mt = 2 * w + i;
            #pragma unroll
            for (int nt = 0; nt < 2; ++nt) {
                const f16v acc = oacc[2 * i + nt];
                #pragma unroll
                for (int g = 0; g < 4; ++g) {
                    const int d0 = 32 * mt + 8 * g + 4 * lh;
                    u2v pk;
                    pk.x = f2bf2(acc[4 * g + 0] * li[nt], acc[4 * g + 1] * li[nt]);
                    pk.y = f2bf2(acc[4 * g + 2] * li[nt], acc[4 * g + 3] * li[nt]);
                    *(u2v*)(sm + L_OBUF + (nt * 16 + (d0 >> 4)) * 1024
                            + (l31 + 32 * ((d0 >> 3) & 1)) * 16 + (d0 & 7) * 2) = pk;
                }
            }
        }
    }
    // ---- rebuild x1pk (epilogue copy)
    #pragma unroll
    for (int i = 0; i < 8; ++i) {
        const int c = t + 256 * i;
        const int q = c >> 5, d0 = (c & 31) * 8;
        const float4 a = *(const float4*)(x1 + (size_t)(qb + q) * DIM + d0);
        const float4 b = *(const float4*)(x1 + (size_t)(qb + q) * DIM + d0 + 4);
        u4v pk;
        pk.x = f2bf2(a.x, a.y); pk.y = f2bf2(a.z, a.w);
        pk.z = f2bf2(b.x, b.y); pk.w = f2bf2(b.z, b.w);
        *(u4v*)(sm + L_X1PK2 + ((q >> 5) * 16 + (d0 >> 4)) * 1024
                + ((q & 31) + 32 * ((d0 >> 3) & 1)) * 16) = pk;
    }
    __syncthreads();
    // ---- combine: E0c^T = wo^T*Ohat^T ; S1^T = W1g^T*x1^T ; write out
    const float gw0 = wsf[WS_GATE + 0], gw1 = wsf[WS_GATE + 1];
    const float ginv = wsf[WS_GATE + 4], gcx1 = wsf[WS_GATE + 5];
    #pragma unroll
    for (int i = 0; i < 2; ++i) {
        const int mt = 2 * w + i;
        f16v e0a = (f16v)0.0f, e1a = (f16v)0.0f, s0a = (f16v)0.0f, s1a = (f16v)0.0f;
        for (int s = 0; s < 16; ++s) {
            const s8v awo = *(const s8v*)(wot + (mt * 16 + s) * 1024 + lane * 16);
            const s8v aw1 = *(const s8v*)(w1t + (mt * 16 + s) * 1024 + lane * 16);
            const s8v bo0 = *(const s8v*)(sm + L_OBUF + s * 1024 + lane * 16);
            const s8v bo1 = *(const s8v*)(sm + L_OBUF + (16 + s) * 1024 + lane * 16);
            const s8v bx0 = *(const s8v*)(sm + L_X1PK2 + s * 1024 + lane * 16);
            const s8v bx1 = *(const s8v*)(sm + L_X1PK2 + (16 + s) * 1024 + lane * 16);
            e0a = MFMA32(awo, bo0, e0a); e1a = MFMA32(awo, bo1, e1a);
            s0a = MFMA32(aw1, bx0, s0a); s1a = MFMA32(aw1, bx1, s1a);
        }
        #pragma unroll
        for (int nt = 0; nt < 2; ++nt) {
            const f16v E = nt ? e1a : e0a;
            const f16v S = nt ? s1a : s0a;
            const int q = 32 * nt + l31;
            const float rrq = *(const float*)(sm + L_RR + q * 4);
            #pragma unroll
            for (int g = 0; g < 4; ++g) {
                const int d0 = 32 * mt + 8 * g + 4 * lh;
                const float4 cv = *(const float4*)(sm + L_CV + d0 * 4);
                const float4 bb = *(const float4*)(sm + L_B1 + d0 * 4);
                const float4 xx = *(const float4*)(x1 + (size_t)(qb + q) * DIM + d0);
                float ev0 = S[4 * g + 0] * rrq + bb.x; ev0 = (ev0 > 0.f) ? ev0 : expm1f(ev0);
                float ev1 = S[4 * g + 1] * rrq + bb.y; ev1 = (ev1 > 0.f) ? ev1 : expm1f(ev1);
                float ev2 = S[4 * g + 2] * rrq + bb.z; ev2 = (ev2 > 0.f) ? ev2 : expm1f(ev2);
                float ev3 = S[4 * g + 3] * rrq + bb.w; ev3 = (ev3 > 0.f) ? ev3 : expm1f(ev3);
                float4 o;
                o.x = ginv * (gcx1 * xx.x + gw0 * E[4 * g + 0] + gw1 * ev0 + cv.x);
                o.y = ginv * (gcx1 * xx.y + gw0 * E[4 * g + 1] + gw1 * ev1 + cv.y);
                o.z = ginv * (gcx1 * xx.z + gw0 * E[4 * g + 2] + gw1 * ev2 + cv.z);
                o.w = ginv * (gcx1 * xx.w + gw0 * E[4 * g + 3] + gw1 * ev3 + cv.w);
                *(float4*)(out + (size_t)(qb + q) * DIM + d0) = o;
            }
        }
    }
}

extern "C" void kernel_launch(void* const* d_in, const int* in_sizes, int n_in,
                              void* d_out, int out_size, void* d_ws, size_t ws_size,
                              hipStream_t stream)
{
    (void)in_sizes; (void)n_in; (void)out_size; (void)ws_size;
    const float* x1    = (const float*)d_in[0];
    const float* x2    = (const float*)d_in[1];
    const float* sim   = (const float*)d_in[2];
    const float* gates = (const float*)d_in[3];
    const float* g1    = (const float*)d_in[4];
    const float* g2    = (const float*)d_in[5];
    const float* w1m   = (const float*)d_in[6];
    const float* b1    = (const float*)d_in[7];
    const float* w2m   = (const float*)d_in[8];
    const float* b2    = (const float*)d_in[9];
    const float* wq    = (const float*)d_in[10];
    const float* wk    = (const float*)d_in[11];
    const float* wv    = (const float*)d_in[12];
    const float* wo    = (const float*)d_in[13];
    const float* va    = (const float*)d_in[14];
    const float* ua    = (const float*)d_in[15];
    const float* wa    = (const float*)d_in[16];
    const float* wf    = (const float*)d_in[17];
    float* ws  = (float*)d_ws;
    float* out = (float*)d_out;

    hipMemsetAsync(ws + WS_ACC, 0, 1024 * sizeof(float), stream);
    hipLaunchKernelGGL(k_colsum1, dim3(N1 / 256), dim3(256), 0, stream, x1, ws);
    hipLaunchKernelGGL(k_x2prep, dim3(N2 / 8), dim3(256), 0, stream,
                       x2, wk, wv, w2m, g2, b2, va, ua, wa, ws);
    hipLaunchKernelGGL(k_wpack, dim3(96), dim3(256), 0, stream, wq, wo, w1m, g1, ws);
    hipLaunchKernelGGL(k_gate, dim3(1), dim3(256), 0, stream, sim, gates, ws);
    hipLaunchKernelGGL(k_pooled, dim3(16), dim3(256), 0, stream, x2, ws);
    hipLaunchKernelGGL(k_cvec, dim3(1), dim3(256), 0, stream, wf, ws);
    hipLaunchKernelGGL(k_flash, dim3(N1 / 64), dim3(256), SMEM_BYTES, stream,
                       x1, b1, ws, out);
}

// Round 3
// 296.423 us; speedup vs baseline: 5.7456x; 1.2153x over previous
//
#include <hip/hip_runtime.h>
#include <math.h>

#define N1 16384
#define N2 4096
#define DIM 256
#define ATT 128

typedef unsigned int uint32;
typedef __attribute__((ext_vector_type(4))) short s4v;
typedef __attribute__((ext_vector_type(8))) short s8v;
typedef __attribute__((ext_vector_type(16))) float f16v;
typedef __attribute__((ext_vector_type(2))) uint32 u2v;
typedef __attribute__((ext_vector_type(4))) uint32 u4v;

union S8U { s8v v; s4v h[2]; };

#define AS1C const __attribute__((address_space(1)))
#define AS3 __attribute__((address_space(3)))

// ---- workspace layout (float offsets) ----
#define WS_KPK 0              // K frag-packed bf16  [4096*256] = 2MB
#define WS_VPK 524288         // V^T frag-packed bf16
#define WS_WQT 1048576        // wq^T A-frag packed bf16 (128KB)
#define WS_WOT 1081344
#define WS_W1T 1114112
#define WS_ACC 1146880        // zeroed: colsum1,colsum2,s2sum,pooled (1024 f)
#define WS_COLSUM1 (WS_ACC)
#define WS_COLSUM2 (WS_ACC+256)
#define WS_S2SUM  (WS_ACC+512)
#define WS_POOLED (WS_ACC+768)
#define WS_ALOGIT (WS_ACC+1024)     // [4096]
#define WS_AW     (WS_ALOGIT+4096)  // [4096]
#define WS_CVEC   (WS_AW+4096)      // [256]
#define WS_GATE   (WS_CVEC+256)     // [8]

// ---- flash LDS layout (bytes): K 64K | V 64K | P 16K | misc ----
#define L_K    0
#define L_V    65536
#define L_P    131072
#define L_LP   147456
#define L_LINV 149504
#define L_RRS  149760
#define L_RR   150016
#define L_X1PK  0          // prologue alias (K region, 32 KB)
#define L_QPAD  65536      // prologue alias (V region, 33 KB)
#define L_OBUF  0          // epilogue alias (K region, 32 KB)
#define L_X1PK2 65536      // epilogue alias (V region, 32 KB)
#define SMEM_BYTES 150272

__device__ __forceinline__ uint32 f2bf1(float f) {
    uint32 u = __float_as_uint(f);
    return (u + 0x7fffu + ((u >> 16) & 1u)) >> 16;
}
__device__ __forceinline__ uint32 f2bf2(float lo, float hi) {
    return f2bf1(lo) | (f2bf1(hi) << 16);
}
#define MFMA32(a, b, c) __builtin_amdgcn_mfma_f32_32x32x16_bf16((a), (b), (c), 0, 0, 0)

// ---------------- column sums of x1 (gate mean) ----------------
__global__ __launch_bounds__(256) void k_colsum1(const float* __restrict__ x1,
                                                 float* __restrict__ ws)
{
    const int t = threadIdx.x;
    const int rbase = blockIdx.x * 64;
    float acc = 0.f;
    for (int r = 0; r < 64; ++r) acc += x1[(size_t)(rbase + r) * DIM + t];
    atomicAdd(&ws[WS_COLSUM1 + t], acc);
}

// ---------------- x2 prep: Kpk, Vpk, SNN-pool, DAMISL logits, colsum2 ----------------
__global__ __launch_bounds__(256) void k_x2prep(const float* __restrict__ x2,
    const float* __restrict__ wk, const float* __restrict__ wv,
    const float* __restrict__ snn_w2, const float* __restrict__ g2,
    const float* __restrict__ b2,
    const float* __restrict__ va, const float* __restrict__ ua,
    const float* __restrict__ wa,
    float* __restrict__ ws)
{
    __shared__ float xs[8][260];
    __shared__ float rr[8];
    __shared__ float hbuf[2][8][132];
    __shared__ float red2[8][2];
    const int t = threadIdx.x;
    const int base = blockIdx.x * 8 * DIM;
    unsigned short* kpk = (unsigned short*)(ws + WS_KPK);
    unsigned short* vpk = (unsigned short*)(ws + WS_VPK);

    for (int i = t; i < 8 * DIM; i += 256) xs[i >> 8][i & 255] = x2[base + i];
    __syncthreads();

    { // column partial sums
        float s = 0.f;
        #pragma unroll
        for (int r = 0; r < 8; ++r) s += xs[r][t];
        atomicAdd(&ws[WS_COLSUM2 + t], s);
    }
    { // rms factors
        const int row = t >> 5, l32 = t & 31;
        float p = 0.f;
        #pragma unroll
        for (int j = 0; j < 8; ++j) { const float v = xs[row][l32 + 32 * j]; p += v * v; }
        #pragma unroll
        for (int off = 16; off > 0; off >>= 1) p += __shfl_down(p, off, 32);
        if (l32 == 0) rr[row] = rsqrtf(p * (1.0f / DIM) + 1e-6f);
    }
    __syncthreads();

    { // K, V, SNN matmuls; thread t = output column d
        float accK[8], accV[8], accS[8];
        #pragma unroll
        for (int r = 0; r < 8; ++r) { accK[r] = 0.f; accV[r] = 0.f; accS[r] = 0.f; }
        for (int k4 = 0; k4 < 64; ++k4) {
            float xk[8][4];
            #pragma unroll
            for (int r = 0; r < 8; ++r) {
                const float4 v = *(const float4*)&xs[r][k4 * 4];
                xk[r][0] = v.x; xk[r][1] = v.y; xk[r][2] = v.z; xk[r][3] = v.w;
            }
            #pragma unroll
            for (int i = 0; i < 4; ++i) {
                const int k = k4 * 4 + i;
                const float wkv = wk[k * DIM + t];
                const float wvv = wv[k * DIM + t];
                const float wsv = g2[k] * snn_w2[k * DIM + t];
                #pragma unroll
                for (int r = 0; r < 8; ++r) {
                    accK[r] = fmaf(xk[r][i], wkv, accK[r]);
                    accV[r] = fmaf(xk[r][i], wvv, accV[r]);
                    accS[r] = fmaf(xk[r][i], wsv, accS[r]);
                }
            }
        }
        const float b2v = b2[t];
        const int d = t;
        float ssum = 0.f;
        #pragma unroll
        for (int r = 0; r < 8; ++r) {
            const int key = blockIdx.x * 8 + r;
            unsigned int offK = (unsigned int)((key >> 6) * 32 + 2 * (d >> 4) + ((key >> 5) & 1)) * 512u
                              + (unsigned int)((key & 31) + 32 * ((d >> 3) & 1)) * 8u + (d & 7);
            kpk[offK] = (unsigned short)f2bf1(accK[r]);
            unsigned int offV = (unsigned int)((key >> 6) * 32 + 4 * (d >> 5) + ((key >> 4) & 3)) * 512u
                              + (unsigned int)((d & 31) + 32 * ((key >> 3) & 1)) * 8u + (key & 7);
            vpk[offV] = (unsigned short)f2bf1(accV[r]);
            const float ev = accS[r] * rr[r] + b2v;
            ssum += (ev > 0.f) ? ev : expm1f(ev);
        }
        atomicAdd(&ws[WS_S2SUM + t], ssum);
    }

    { // DAMISL gated-attention logits
        const int j = t & 127;
        const int half = t >> 7;
        const float* __restrict__ W = half ? ua : va;
        float acc8[8];
        #pragma unroll
        for (int r = 0; r < 8; ++r) acc8[r] = 0.f;
        for (int k4 = 0; k4 < 64; ++k4) {
            float xk[8][4];
            #pragma unroll
            for (int r = 0; r < 8; ++r) {
                const float4 v = *(const float4*)&xs[r][k4 * 4];
                xk[r][0] = v.x; xk[r][1] = v.y; xk[r][2] = v.z; xk[r][3] = v.w;
            }
            #pragma unroll
            for (int i = 0; i < 4; ++i) {
                const float wv_ = W[(k4 * 4 + i) * ATT + j];
                #pragma unroll
                for (int r = 0; r < 8; ++r) acc8[r] = fmaf(xk[r][i], wv_, acc8[r]);
            }
        }
        #pragma unroll
        for (int r = 0; r < 8; ++r) hbuf[half][r][j] = acc8[r];
    }
    __syncthreads();
    if (t < 128) {
        const float waj = wa[t];
        #pragma unroll
        for (int r = 0; r < 8; ++r) {
            const float hv = hbuf[0][r][t];
            const float hu = hbuf[1][r][t];
            float p = tanhf(hv) * (1.0f / (1.0f + expf(-hu))) * waj;
            #pragma unroll
            for (int off = 32; off > 0; off >>= 1) p += __shfl_down(p, off, 64);
            if ((t & 63) == 0) red2[r][t >> 6] = p;
        }
    }
    __syncthreads();
    if (t < 8) ws[WS_ALOGIT + blockIdx.x * 8 + t] = red2[t][0] + red2[t][1];
}

// ---------------- weight packing: wq^T / wo^T / (g1*snn_w1)^T frags ----------------
__global__ __launch_bounds__(256) void k_wpack(const float* __restrict__ wq,
    const float* __restrict__ wo, const float* __restrict__ snn_w1,
    const float* __restrict__ g1, float* __restrict__ ws)
{
    const int b = blockIdx.x;
    const int mat = b >> 5, chunk = b & 31;
    const int t = threadIdx.x;
    const float* W = (mat == 0) ? wq : (mat == 1) ? wo : snn_w1;
    unsigned short* dst = (unsigned short*)(ws + ((mat == 0) ? WS_WQT : (mat == 1) ? WS_WOT : WS_W1T));
    const int e0 = chunk * 2048 + t * 8;
    const int k = e0 >> 8, n0 = e0 & 255;
    const float4 v0 = *(const float4*)(W + k * 256 + n0);
    const float4 v1 = *(const float4*)(W + k * 256 + n0 + 4);
    const float sc = (mat == 2) ? g1[k] : 1.0f;
    float vals[8] = {v0.x, v0.y, v0.z, v0.w, v1.x, v1.y, v1.z, v1.w};
    const unsigned int sbase = (unsigned int)(k >> 4) * 512u + 32u * ((k >> 3) & 1) * 8u + (k & 7);
    #pragma unroll
    for (int jj = 0; jj < 8; ++jj) {
        const int n = n0 + jj;
        unsigned int off = (unsigned int)(n >> 5) * 16u * 512u + sbase + (unsigned int)(n & 31) * 8u;
        dst[off] = (unsigned short)f2bf1(vals[jj] * sc);
    }
}

// ---------------- block reductions ----------------
__device__ __forceinline__ float block_sum256(float v, float* red, int t)
{
    red[t] = v; __syncthreads();
    for (int s = 128; s > 0; s >>= 1) { if (t < s) red[t] += red[t + s]; __syncthreads(); }
    const float r = red[0]; __syncthreads(); return r;
}
__device__ __forceinline__ float block_max256(float v, float* red, int t)
{
    red[t] = v; __syncthreads();
    for (int s = 128; s > 0; s >>= 1) { if (t < s) red[t] = fmaxf(red[t], red[t + s]); __syncthreads(); }
    const float r = red[0]; __syncthreads(); return r;
}

// ---------------- gate (cosine top-2) + DAMISL softmax ----------------
__global__ __launch_bounds__(256) void k_gate(const float* __restrict__ sim,
    const float* __restrict__ gates, float* __restrict__ ws)
{
    __shared__ float red[256];
    __shared__ float sc[4];
    const int t = threadIdx.x;
    const float f = 0.5f * (ws[WS_COLSUM1 + t] * (1.0f / N1) +
                            ws[WS_COLSUM2 + t] * (1.0f / N2));
    const float fs = block_sum256(f * f, red, t);
    const float rsqf = rsqrtf(fs + 1e-8f);
    for (int e = 0; e < 4; ++e) {
        const float sv = sim[e * DIM + t];
        const float n2 = block_sum256(sv * sv, red, t);
        const float dt = block_sum256(sv * f, red, t);
        if (t == 0) sc[e] = dt * rsqf * rsqrtf(n2 + 1e-8f);
    }
    __syncthreads();
    if (t == 0) {
        float a = -1e30f, b = -1e30f;
        #pragma unroll
        for (int e = 0; e < 4; ++e) {
            const float v = sc[e];
            if (v > a) { b = a; a = v; } else if (v > b) { b = v; }
        }
        float w[4]; int ns = 0;
        #pragma unroll
        for (int e = 0; e < 4; ++e) {
            const bool keep = (sc[e] >= b) && (sc[e] > gates[e]);
            w[e] = keep ? sc[e] : 0.f;
            if (w[e] > 0.f) ns++;
        }
        if (ns < 1) ns = 1;
        ws[WS_GATE + 0] = w[0]; ws[WS_GATE + 1] = w[1];
        ws[WS_GATE + 2] = w[2]; ws[WS_GATE + 3] = w[3];
        ws[WS_GATE + 4] = 1.0f / (float)ns;
        ws[WS_GATE + 5] = w[0] + w[2] + w[3];
    }
    __syncthreads();
    float mx = -1e30f;
    for (int i = t; i < N2; i += 256) mx = fmaxf(mx, ws[WS_ALOGIT + i]);
    mx = block_max256(mx, red, t);
    float sm = 0.f;
    for (int i = t; i < N2; i += 256) {
        const float e_ = expf(ws[WS_ALOGIT + i] - mx);
        ws[WS_AW + i] = e_;
        sm += e_;
    }
    sm = block_sum256(sm, red, t);
    const float is = 1.0f / sm;
    for (int i = t; i < N2; i += 256) ws[WS_AW + i] *= is;
}

// ---------------- pooled = a^T x2 ----------------
__global__ __launch_bounds__(256) void k_pooled(const float* __restrict__ x2,
                                                float* __restrict__ ws)
{
    const int t = threadIdx.x;
    const int rbase = blockIdx.x * 64;
    float acc = 0.f;
    for (int r = 0; r < 64; ++r)
        acc = fmaf(ws[WS_AW + rbase + r], x2[(size_t)(rbase + r) * DIM + t], acc);
    atomicAdd(&ws[WS_POOLED + t], acc);
}

// ---------------- cvec = w1*s2mean + w2*(pooled@wf) ----------------
__global__ __launch_bounds__(256) void k_cvec(const float* __restrict__ wf,
                                              float* __restrict__ ws)
{
    __shared__ float pl[256];
    const int t = threadIdx.x;
    pl[t] = ws[WS_POOLED + t];
    __syncthreads();
    float acc = 0.f;
    for (int k = 0; k < 256; ++k) acc = fmaf(pl[k], wf[k * DIM + t], acc);
    const float w1 = ws[WS_GATE + 1], w2 = ws[WS_GATE + 2];
    ws[WS_CVEC + t] = w1 * (ws[WS_S2SUM + t] * (1.0f / N2)) + w2 * acc;
}

// ---------------- MFMA flash attention + fused epilogue ----------------
// 512 threads (8 waves, 2/SIMD), TQ=64, TK=128, single K/V bufs with
// phase-shifted staging: 2 barriers/tile, each drain covered by a compute phase.
__global__ __launch_bounds__(512, 2) void k_flash(
    const float* __restrict__ x1, const float* __restrict__ b1,
    const float* __restrict__ wsf, float* __restrict__ out)
{
    extern __shared__ char sm[];
    const int t = threadIdx.x;
    const int w = t >> 6;
    const int lane = t & 63;
    const int l31 = lane & 31;
    const int lh = lane >> 5;
    const int qb = blockIdx.x * 64;
    const int kh = w >> 1, qh = w & 1;     // S-phase roles
    const int qp = w & 1, dpair = w >> 1;  // PV-phase roles
    const char* wsb = (const char*)wsf;
    const char* kpk = wsb + (size_t)WS_KPK * 4;
    const char* vpk = wsb + (size_t)WS_VPK * 4;
    const char* wqt = wsb + (size_t)WS_WQT * 4;
    const char* wot = wsb + (size_t)WS_WOT * 4;
    const char* w1t = wsb + (size_t)WS_W1T * 4;

    auto stage64 = [&](const char* gbase, int ldsoff) {
        #pragma unroll
        for (int i = 0; i < 8; ++i) {
            const int c = w * 8 + i;
            __builtin_amdgcn_global_load_lds(
                (AS1C uint32*)(gbase + c * 1024 + lane * 16),
                (AS3 uint32*)(sm + ldsoff + c * 1024), 16, 0, 0);
        }
    };

    // ---- prologue: x1 frags + rms partials
    #pragma unroll
    for (int i = 0; i < 4; ++i) {
        const int c = t + 512 * i;
        const int q = c >> 5, d0 = (c & 31) * 8;
        const float4 a = *(const float4*)(x1 + (size_t)(qb + q) * DIM + d0);
        const float4 b = *(const float4*)(x1 + (size_t)(qb + q) * DIM + d0 + 4);
        float ss = a.x*a.x + a.y*a.y + a.z*a.z + a.w*a.w
                 + b.x*b.x + b.y*b.y + b.z*b.z + b.w*b.w;
        #pragma unroll
        for (int o = 16; o > 0; o >>= 1) ss += __shfl_down(ss, o, 32);
        if ((t & 31) == 0) *(float*)(sm + L_RRS + q * 4) = ss;
        u4v pk;
        pk.x = f2bf2(a.x, a.y); pk.y = f2bf2(a.z, a.w);
        pk.z = f2bf2(b.x, b.y); pk.w = f2bf2(b.z, b.w);
        *(u4v*)(sm + L_X1PK + ((q >> 5) * 16 + (d0 >> 4)) * 1024
                + ((q & 31) + 32 * ((d0 >> 3) & 1)) * 16) = pk;
    }
    __syncthreads();
    if (t < 64) {
        const float s2 = *(const float*)(sm + L_RRS + t * 4);
        *(float*)(sm + L_RR + t * 4) = rsqrtf(s2 * (1.0f / DIM) + 1e-6f);
    }
    // ---- Q^T = wq^T * x1^T -> QPAD [q][d] bf16 (wave w owns d-chunk w, both q halves)
    #pragma unroll
    for (int i = 0; i < 2; ++i) {
        const int mt = w, qt = i;
        f16v qa = (f16v)0.0f;
        #pragma unroll
        for (int s = 0; s < 16; ++s) {
            const s8v a  = *(const s8v*)(wqt + (mt * 16 + s) * 1024 + lane * 16);
            const s8v bb = *(const s8v*)(sm + L_X1PK + (qt * 16 + s) * 1024 + lane * 16);
            qa = MFMA32(a, bb, qa);
        }
        const int q = qt * 32 + l31;
        #pragma unroll
        for (int g = 0; g < 4; ++g) {
            const int d0 = 32 * mt + 8 * g + 4 * lh;
            u2v pk;
            pk.x = f2bf2(qa[4 * g + 0], qa[4 * g + 1]);
            pk.y = f2bf2(qa[4 * g + 2], qa[4 * g + 3]);
            *(u2v*)(sm + L_QPAD + q * 520 + d0 * 2) = pk;
        }
    }
    __syncthreads();
    // ---- load Q B-frags (for qh half) into regs
    s8v qf[16];
    {
        const char* qbase = sm + L_QPAD + (qh * 32 + l31) * 520 + lh * 16;
        #pragma unroll
        for (int s = 0; s < 16; ++s) {
            S8U u;
            u.h[0] = *(const s4v*)(qbase + s * 32);
            u.h[1] = *(const s4v*)(qbase + s * 32 + 8);
            qf[s] = u.v;
        }
    }
    // stage K(0) (clobbers X1PK region only; QPAD lives in V region)
    stage64(kpk, L_K);
    __syncthreads();   // drain K(0); all waves past QPAD reads

    f16v oacc0 = (f16v)0.0f, oacc1 = (f16v)0.0f;
    float lsum = 0.0f;

    // ---- main loop: 32 tiles of 128 keys
    for (int tile = 0; tile < 32; ++tile) {
        stage64(vpk + (size_t)tile * 65536, L_V);
        // S^T = K(kh quarter) * Q^T(qh half)
        f16v sacc = (f16v)0.0f;
        #pragma unroll
        for (int s = 0; s < 16; ++s) {
            const s8v a = *(const s8v*)(sm + L_K
                + ((kh >> 1) * 32 + 2 * s + (kh & 1)) * 1024 + lane * 16);
            sacc = MFMA32(a, qf[s], sacc);
        }
        // exp (max-free), pack P -> LDS B-frags
        #pragma unroll
        for (int g = 0; g < 4; ++g) {
            const float p0 = __expf(sacc[4 * g + 0] * 0.0625f);
            const float p1 = __expf(sacc[4 * g + 1] * 0.0625f);
            const float p2 = __expf(sacc[4 * g + 2] * 0.0625f);
            const float p3 = __expf(sacc[4 * g + 3] * 0.0625f);
            lsum += (p0 + p1) + (p2 + p3);
            const int keyo = 32 * kh + 8 * g + 4 * lh;
            const int kc = keyo >> 4, ko = keyo & 15;
            u2v pk; pk.x = f2bf2(p0, p1); pk.y = f2bf2(p2, p3);
            *(u2v*)(sm + L_P + (qh * 8 + kc) * 1024
                    + (l31 + 32 * (ko >> 3)) * 16 + (ko & 7) * 2) = pk;
        }
        __syncthreads();   // barrier A: drains V(tile); P visible; K free
        if (tile < 31) stage64(kpk + (size_t)(tile + 1) * 65536, L_K);
        // O^T += V^T * P^T  (wave: d-chunks 2*dpair, 2*dpair+1; q half qp)
        s8v pf[8];
        #pragma unroll
        for (int kc = 0; kc < 8; ++kc)
            pf[kc] = *(const s8v*)(sm + L_P + (qp * 8 + kc) * 1024 + lane * 16);
        #pragma unroll
        for (int kc = 0; kc < 8; ++kc) {
            const int sub = (kc >> 2) * 32, k3 = kc & 3;
            const s8v a0 = *(const s8v*)(sm + L_V + (sub + 4 * (2 * dpair) + k3) * 1024 + lane * 16);
            const s8v a1 = *(const s8v*)(sm + L_V + (sub + 4 * (2 * dpair + 1) + k3) * 1024 + lane * 16);
            oacc0 = MFMA32(a0, pf[kc], oacc0);
            oacc1 = MFMA32(a1, pf[kc], oacc1);
        }
        __syncthreads();   // barrier B: drains K(tile+1); V/P free
    }

    // ---- softmax denominators
    *(float*)(sm + L_LP + ((w * 2 + lh) * 32 + l31) * 4) = lsum;
    __syncthreads();
    if (t < 64) {
        const int qh_ = t >> 5, c = t & 31;
        const float* lp = (const float*)(sm + L_LP);
        float l = 0.f;
        #pragma unroll
        for (int k2 = 0; k2 < 4; ++k2)
            l += lp[((k2 * 2 + qh_) * 2 + 0) * 32 + c]
               + lp[((k2 * 2 + qh_) * 2 + 1) * 32 + c];
        *(float*)(sm + L_LINV + t * 4) = 1.0f / l;
    }
    __syncthreads();
    // ---- pack Ohat = O/l into OBUF B-frags
    {
        const float li = *(const float*)(sm + L_LINV + (qp * 32 + l31) * 4);
        #pragma unroll
        for (int half = 0; half < 2; ++half) {
            const f16v acc = half ? oacc1 : oacc0;
            const int dc = 2 * dpair + half;
            #pragma unroll
            for (int g = 0; g < 4; ++g) {
                const int d0 = dc * 32 + 8 * g + 4 * lh;
                u2v pk;
                pk.x = f2bf2(acc[4 * g + 0] * li, acc[4 * g + 1] * li);
                pk.y = f2bf2(acc[4 * g + 2] * li, acc[4 * g + 3] * li);
                *(u2v*)(sm + L_OBUF + (qp * 16 + (d0 >> 4)) * 1024
                        + (l31 + 32 * ((d0 >> 3) & 1)) * 16 + (d0 & 7) * 2) = pk;
            }
        }
    }
    // ---- rebuild x1 frags (epilogue copy, V region)
    #pragma unroll
    for (int i = 0; i < 4; ++i) {
        const int c = t + 512 * i;
        const int q = c >> 5, d0 = (c & 31) * 8;
        const float4 a = *(const float4*)(x1 + (size_t)(qb + q) * DIM + d0);
        const float4 b = *(const float4*)(x1 + (size_t)(qb + q) * DIM + d0 + 4);
        u4v pk;
        pk.x = f2bf2(a.x, a.y); pk.y = f2bf2(a.z, a.w);
        pk.z = f2bf2(b.x, b.y); pk.w = f2bf2(b.z, b.w);
        *(u4v*)(sm + L_X1PK2 + ((q >> 5) * 16 + (d0 >> 4)) * 1024
                + ((q & 31) + 32 * ((d0 >> 3) & 1)) * 16) = pk;
    }
    __syncthreads();
    // ---- combine: E0c^T = wo^T*Ohat^T ; S1^T = W1g^T*x1^T ; write out
    const float gw0 = wsf[WS_GATE + 0], gw1 = wsf[WS_GATE + 1];
    const float ginv = wsf[WS_GATE + 4], gcx1 = wsf[WS_GATE + 5];
    #pragma unroll
    for (int i = 0; i < 2; ++i) {
        const int mt = w, qt = i;
        f16v ea = (f16v)0.0f, sa = (f16v)0.0f;
        for (int s = 0; s < 16; ++s) {
            const s8v awo = *(const s8v*)(wot + (mt * 16 + s) * 1024 + lane * 16);
            const s8v aw1 = *(const s8v*)(w1t + (mt * 16 + s) * 1024 + lane * 16);
            const s8v bo = *(const s8v*)(sm + L_OBUF + (qt * 16 + s) * 1024 + lane * 16);
            const s8v bx = *(const s8v*)(sm + L_X1PK2 + (qt * 16 + s) * 1024 + lane * 16);
            ea = MFMA32(awo, bo, ea);
            sa = MFMA32(aw1, bx, sa);
        }
        const int q = qt * 32 + l31;
        const float rrq = *(const float*)(sm + L_RR + q * 4);
        #pragma unroll
        for (int g = 0; g < 4; ++g) {
            const int d0 = 32 * mt + 8 * g + 4 * lh;
            const float4 cv = *(const float4*)(wsf + WS_CVEC + d0);
            const float4 bb = *(const float4*)(b1 + d0);
            const float4 xx = *(const float4*)(x1 + (size_t)(qb + q) * DIM + d0);
            float ev0 = sa[4 * g + 0] * rrq + bb.x; ev0 = (ev0 > 0.f) ? ev0 : expm1f(ev0);
            float ev1 = sa[4 * g + 1] * rrq + bb.y; ev1 = (ev1 > 0.f) ? ev1 : expm1f(ev1);
            float ev2 = sa[4 * g + 2] * rrq + bb.z; ev2 = (ev2 > 0.f) ? ev2 : expm1f(ev2);
            float ev3 = sa[4 * g + 3] * rrq + bb.w; ev3 = (ev3 > 0.f) ? ev3 : expm1f(ev3);
            float4 o;
            o.x = ginv * (gcx1 * xx.x + gw0 * ea[4 * g + 0] + gw1 * ev0 + cv.x);
            o.y = ginv * (gcx1 * xx.y + gw0 * ea[4 * g + 1] + gw1 * ev1 + cv.y);
            o.z = ginv * (gcx1 * xx.z + gw0 * ea[4 * g + 2] + gw1 * ev2 + cv.z);
            o.w = ginv * (gcx1 * xx.w + gw0 * ea[4 * g + 3] + gw1 * ev3 + cv.w);
            *(float4*)(out + (size_t)(qb + q) * DIM + d0) = o;
        }
    }
}

extern "C" void kernel_launch(void* const* d_in, const int* in_sizes, int n_in,
                              void* d_out, int out_size, void* d_ws, size_t ws_size,
                              hipStream_t stream)
{
    (void)in_sizes; (void)n_in; (void)out_size; (void)ws_size;
    const float* x1    = (const float*)d_in[0];
    const float* x2    = (const float*)d_in[1];
    const float* sim   = (const float*)d_in[2];
    const float* gates = (const float*)d_in[3];
    const float* g1    = (const float*)d_in[4];
    const float* g2    = (const float*)d_in[5];
    const float* w1m   = (const float*)d_in[6];
    const float* b1    = (const float*)d_in[7];
    const float* w2m   = (const float*)d_in[8];
    const float* b2    = (const float*)d_in[9];
    const float* wq    = (const float*)d_in[10];
    const float* wk    = (const float*)d_in[11];
    const float* wv    = (const float*)d_in[12];
    const float* wo    = (const float*)d_in[13];
    const float* va    = (const float*)d_in[14];
    const float* ua    = (const float*)d_in[15];
    const float* wa    = (const float*)d_in[16];
    const float* wf    = (const float*)d_in[17];
    float* ws  = (float*)d_ws;
    float* out = (float*)d_out;

    hipMemsetAsync(ws + WS_ACC, 0, 1024 * sizeof(float), stream);
    hipLaunchKernelGGL(k_colsum1, dim3(N1 / 64), dim3(256), 0, stream, x1, ws);
    hipLaunchKernelGGL(k_x2prep, dim3(N2 / 8), dim3(256), 0, stream,
                       x2, wk, wv, w2m, g2, b2, va, ua, wa, ws);
    hipLaunchKernelGGL(k_wpack, dim3(96), dim3(256), 0, stream, wq, wo, w1m, g1, ws);
    hipLaunchKernelGGL(k_gate, dim3(1), dim3(256), 0, stream, sim, gates, ws);
    hipLaunchKernelGGL(k_pooled, dim3(N2 / 64), dim3(256), 0, stream, x2, ws);
    hipLaunchKernelGGL(k_cvec, dim3(1), dim3(256), 0, stream, wf, ws);
    hipLaunchKernelGGL(k_flash, dim3(N1 / 64), dim3(512), SMEM_BYTES, stream,
                       x1, b1, ws, out);
}

// Round 4
// 278.346 us; speedup vs baseline: 6.1187x; 1.0649x over previous
//
#include <hip/hip_runtime.h>
#include <math.h>

#define N1 16384
#define N2 4096
#define DIM 256
#define ATT 128

typedef unsigned int uint32;
typedef __attribute__((ext_vector_type(4))) short s4v;
typedef __attribute__((ext_vector_type(8))) short s8v;
typedef __attribute__((ext_vector_type(16))) float f16v;
typedef __attribute__((ext_vector_type(2))) uint32 u2v;
typedef __attribute__((ext_vector_type(4))) uint32 u4v;

union S8U { s8v v; s4v h[2]; };

#define AS1C const __attribute__((address_space(1)))
#define AS3 __attribute__((address_space(3)))

// ---- workspace layout (float offsets) ----
#define WS_KPK 0              // K frag-packed bf16  [4096*256] = 2MB
#define WS_VPK 524288         // V^T frag-packed bf16
#define WS_WQT 1048576        // packed weight frags, 128KB each (256x256)
#define WS_WOT 1081344
#define WS_W1T 1114112
#define WS_WKT 1146880
#define WS_WVT 1179648
#define WS_W2T 1212416
#define WS_VAT 1245184        // 64KB (256x128)
#define WS_UAT 1261568
#define WS_ACC 1277952        // zeroed: colsum1,colsum2,s2sum,pooled (1024 f)
#define WS_COLSUM1 (WS_ACC)
#define WS_COLSUM2 (WS_ACC+256)
#define WS_S2SUM  (WS_ACC+512)
#define WS_POOLED (WS_ACC+768)
#define WS_ALOGIT (WS_ACC+1024)     // [4096]
#define WS_AW     (WS_ALOGIT+4096)  // [4096]
#define WS_CVEC   (WS_AW+4096)      // [256]
#define WS_GATE   (WS_CVEC+256)     // [8]

// ---- flash LDS layout (bytes): K 64K | V 64K | P 16K | misc ----
#define L_K    0
#define L_V    65536
#define L_P    131072
#define L_LP   147456
#define L_LINV 149504
#define L_RRS  149760
#define L_RR   150016
#define L_X1PK  0          // prologue alias (K region, 32 KB)
#define L_QPAD  65536      // prologue alias (V region, 33 KB)
#define L_OBUF  0          // epilogue alias (K region, 32 KB)
#define L_X1PK2 65536      // epilogue alias (V region, 32 KB)
#define SMEM_BYTES 150272

__device__ __forceinline__ uint32 f2bf1(float f) {
    uint32 u = __float_as_uint(f);
    return (u + 0x7fffu + ((u >> 16) & 1u)) >> 16;
}
__device__ __forceinline__ uint32 f2bf2(float lo, float hi) {
    return f2bf1(lo) | (f2bf1(hi) << 16);
}
#define MFMA32(a, b, c) __builtin_amdgcn_mfma_f32_32x32x16_bf16((a), (b), (c), 0, 0, 0)

// ---------------- merged column sums: x1 -> COLSUM1, x2 -> COLSUM2 ----------------
__global__ __launch_bounds__(256) void k_colsum12(const float* __restrict__ x1,
                                                  const float* __restrict__ x2,
                                                  float* __restrict__ ws)
{
    const int t = threadIdx.x;
    const int b = blockIdx.x;
    const float* src = (b < 256) ? x1 : x2;
    const int rbase = ((b < 256) ? b : (b - 256)) * 64;
    const int dsti = (b < 256) ? (WS_COLSUM1 + t) : (WS_COLSUM2 + t);
    float acc = 0.f;
    for (int r = 0; r < 64; ++r) acc += src[(size_t)(rbase + r) * DIM + t];
    atomicAdd(&ws[dsti], acc);
}

// ---------------- weight packing: 8 matrices -> A-frag layout of W^T ----------------
__global__ __launch_bounds__(256) void k_wpack(const float* __restrict__ wq,
    const float* __restrict__ wo, const float* __restrict__ snn_w1,
    const float* __restrict__ wk, const float* __restrict__ wv,
    const float* __restrict__ snn_w2,
    const float* __restrict__ va, const float* __restrict__ ua,
    const float* __restrict__ g1, const float* __restrict__ g2,
    float* __restrict__ ws)
{
    const int b = blockIdx.x;
    const int t = threadIdx.x;
    int mat, chunk, ncols;
    if (b < 192) { mat = b >> 5; chunk = b & 31; ncols = 256; }
    else { mat = 6 + ((b - 192) >> 4); chunk = (b - 192) & 15; ncols = 128; }
    const float* W;
    int dstoff;
    switch (mat) {
        case 0: W = wq;     dstoff = WS_WQT; break;
        case 1: W = wo;     dstoff = WS_WOT; break;
        case 2: W = snn_w1; dstoff = WS_W1T; break;
        case 3: W = wk;     dstoff = WS_WKT; break;
        case 4: W = wv;     dstoff = WS_WVT; break;
        case 5: W = snn_w2; dstoff = WS_W2T; break;
        case 6: W = va;     dstoff = WS_VAT; break;
        default: W = ua;    dstoff = WS_UAT; break;
    }
    unsigned short* dst = (unsigned short*)(ws + dstoff);
    const int e0 = chunk * 2048 + t * 8;
    const int k = (ncols == 256) ? (e0 >> 8) : (e0 >> 7);
    const int n0 = (ncols == 256) ? (e0 & 255) : (e0 & 127);
    const float4 v0 = *(const float4*)(W + k * ncols + n0);
    const float4 v1 = *(const float4*)(W + k * ncols + n0 + 4);
    const float sc = (mat == 2) ? g1[k] : ((mat == 5) ? g2[k] : 1.0f);
    float vals[8] = {v0.x, v0.y, v0.z, v0.w, v1.x, v1.y, v1.z, v1.w};
    const unsigned int sbase = (unsigned int)(k >> 4) * 512u + 32u * ((k >> 3) & 1) * 8u + (k & 7);
    #pragma unroll
    for (int jj = 0; jj < 8; ++jj) {
        const int n = n0 + jj;
        unsigned int off = (unsigned int)(n >> 5) * 16u * 512u + sbase + (unsigned int)(n & 31) * 8u;
        dst[off] = (unsigned short)f2bf1(vals[jj] * sc);
    }
}

// ---------------- x2 prep via MFMA: Kpk, Vpk, SNN-pool, DAMISL logits ----------------
// 32 tokens/block, 512 threads (8 waves). All gemms in bf16 MFMA from LDS frags.
__global__ __launch_bounds__(512) void k_x2prep2(const float* __restrict__ x2,
    const float* __restrict__ b2, const float* __restrict__ wa,
    float* __restrict__ ws)
{
    __shared__ char xps[16384];     // x2^T frags: 16 chunks x 1KB
    __shared__ float rrs[32];
    __shared__ float dlp[4][32];
    const int t = threadIdx.x;
    const int w = t >> 6;
    const int lane = t & 63;
    const int l31 = lane & 31;
    const int lh = lane >> 5;
    const int b = blockIdx.x;
    const int tb = b * 32;
    unsigned short* kpk = (unsigned short*)(ws + WS_KPK);
    unsigned short* vpk = (unsigned short*)(ws + WS_VPK);
    const char* wsb = (const char*)ws;
    const char* wkt = wsb + (size_t)WS_WKT * 4;
    const char* wvt = wsb + (size_t)WS_WVT * 4;
    const char* w2t = wsb + (size_t)WS_W2T * 4;
    const char* vat = wsb + (size_t)WS_VAT * 4;
    const char* uat = wsb + (size_t)WS_UAT * 4;

    // ---- load + pack x2 tile (32 x 256), rms partials
    #pragma unroll
    for (int i = 0; i < 2; ++i) {
        const int c = t + 512 * i;
        const int tk = c >> 5, d0 = (c & 31) * 8;
        const float4 a = *(const float4*)(x2 + (size_t)(tb + tk) * DIM + d0);
        const float4 bb = *(const float4*)(x2 + (size_t)(tb + tk) * DIM + d0 + 4);
        float ss = a.x*a.x + a.y*a.y + a.z*a.z + a.w*a.w
                 + bb.x*bb.x + bb.y*bb.y + bb.z*bb.z + bb.w*bb.w;
        #pragma unroll
        for (int o = 16; o > 0; o >>= 1) ss += __shfl_down(ss, o, 32);
        if ((t & 31) == 0) rrs[tk] = ss;
        u4v pk;
        pk.x = f2bf2(a.x, a.y); pk.y = f2bf2(a.z, a.w);
        pk.z = f2bf2(bb.x, bb.y); pk.w = f2bf2(bb.z, bb.w);
        *(u4v*)(xps + (d0 >> 4) * 1024 + (tk + 32 * ((d0 >> 3) & 1)) * 16) = pk;
    }
    __syncthreads();

    // ---- K^T = wk^T * x2^T : wave w = dout chunk w ----
    {
        f16v kacc = (f16v)0.0f;
        #pragma unroll
        for (int s = 0; s < 16; ++s) {
            const s8v a = *(const s8v*)(wkt + (w * 16 + s) * 1024 + lane * 16);
            const s8v bb = *(const s8v*)(xps + s * 1024 + lane * 16);
            kacc = MFMA32(a, bb, kacc);
        }
        #pragma unroll
        for (int g = 0; g < 4; ++g) {
            // d rows = 32w + 8g + 4lh + (0..3); key col = tb + l31
            const unsigned int chunkK = (unsigned int)((b >> 1) * 32 + 2 * (2 * w + (g >> 1)) + (b & 1));
            const unsigned int off = chunkK * 512u + (unsigned int)(l31 + 32 * (g & 1)) * 8u + 4u * lh;
            u2v pk;
            pk.x = f2bf2(kacc[4 * g + 0], kacc[4 * g + 1]);
            pk.y = f2bf2(kacc[4 * g + 2], kacc[4 * g + 3]);
            *(u2v*)(kpk + off) = pk;
        }
    }
    // ---- V = x2 * wv : wave w = dout n-chunk w ----
    {
        f16v vacc = (f16v)0.0f;
        #pragma unroll
        for (int s = 0; s < 16; ++s) {
            const s8v a = *(const s8v*)(xps + s * 1024 + lane * 16);
            const s8v bb = *(const s8v*)(wvt + (w * 16 + s) * 1024 + lane * 16);
            vacc = MFMA32(a, bb, vacc);
        }
        #pragma unroll
        for (int g = 0; g < 4; ++g) {
            // token rows tk = 8g+4lh+(0..3); dout col = 32w + l31
            const unsigned int chunkV = (unsigned int)((b >> 1) * 32 + 4 * w + 2 * (b & 1) + (g >> 1));
            const unsigned int off = chunkV * 512u + (unsigned int)(l31 + 32 * (g & 1)) * 8u + 4u * lh;
            u2v pk;
            pk.x = f2bf2(vacc[4 * g + 0], vacc[4 * g + 1]);
            pk.y = f2bf2(vacc[4 * g + 2], vacc[4 * g + 3]);
            *(u2v*)(vpk + off) = pk;
        }
    }
    // ---- SNN: elu(rms(x2)@w2g + b2), column-sum over tokens -> S2SUM ----
    {
        f16v sacc = (f16v)0.0f;
        #pragma unroll
        for (int s = 0; s < 16; ++s) {
            const s8v a = *(const s8v*)(w2t + (w * 16 + s) * 1024 + lane * 16);
            const s8v bb = *(const s8v*)(xps + s * 1024 + lane * 16);
            sacc = MFMA32(a, bb, sacc);
        }
        const float rrl = rsqrtf(rrs[l31] * (1.0f / DIM) + 1e-6f);
        #pragma unroll
        for (int g = 0; g < 4; ++g) {
            const float4 bb = *(const float4*)(b2 + 32 * w + 8 * g + 4 * lh);
            #pragma unroll
            for (int jj = 0; jj < 4; ++jj) {
                float v = sacc[4 * g + jj] * rrl + ((const float*)&bb)[jj];
                v = (v > 0.f) ? v : expm1f(v);
                v += __shfl_xor(v, 16); v += __shfl_xor(v, 8);
                v += __shfl_xor(v, 4);  v += __shfl_xor(v, 2);
                v += __shfl_xor(v, 1);
                if (l31 == 0) atomicAdd(&ws[WS_S2SUM + 32 * w + 8 * g + 4 * lh + jj], v);
            }
        }
    }
    // ---- DAMISL H = tanh(x2@va)*sig(x2@ua), logits -> ALOGIT (waves 0..3) ----
    if (w < 4) {
        f16v hv = (f16v)0.0f, hu = (f16v)0.0f;
        #pragma unroll
        for (int s = 0; s < 16; ++s) {
            const s8v bb = *(const s8v*)(xps + s * 1024 + lane * 16);
            const s8v a1 = *(const s8v*)(vat + (w * 16 + s) * 1024 + lane * 16);
            const s8v a2 = *(const s8v*)(uat + (w * 16 + s) * 1024 + lane * 16);
            hv = MFMA32(a1, bb, hv);
            hu = MFMA32(a2, bb, hu);
        }
        float acc = 0.f;
        #pragma unroll
        for (int g = 0; g < 4; ++g) {
            const float4 w4 = *(const float4*)(wa + 32 * w + 8 * g + 4 * lh);
            #pragma unroll
            for (int jj = 0; jj < 4; ++jj) {
                acc += tanhf(hv[4 * g + jj]) * (1.0f / (1.0f + expf(-hu[4 * g + jj])))
                       * ((const float*)&w4)[jj];
            }
        }
        acc += __shfl_xor(acc, 32);
        if (lh == 0) dlp[w][l31] = acc;
    }
    __syncthreads();
    if (t < 32) ws[WS_ALOGIT + tb + t] = dlp[0][t] + dlp[1][t] + dlp[2][t] + dlp[3][t];
}

// ---------------- block reductions ----------------
__device__ __forceinline__ float block_sum256(float v, float* red, int t)
{
    red[t] = v; __syncthreads();
    for (int s = 128; s > 0; s >>= 1) { if (t < s) red[t] += red[t + s]; __syncthreads(); }
    const float r = red[0]; __syncthreads(); return r;
}
__device__ __forceinline__ float block_max256(float v, float* red, int t)
{
    red[t] = v; __syncthreads();
    for (int s = 128; s > 0; s >>= 1) { if (t < s) red[t] = fmaxf(red[t], red[t + s]); __syncthreads(); }
    const float r = red[0]; __syncthreads(); return r;
}

// ---------------- gate (cosine top-2) + DAMISL softmax ----------------
__global__ __launch_bounds__(256) void k_gate(const float* __restrict__ sim,
    const float* __restrict__ gates, float* __restrict__ ws)
{
    __shared__ float red[256];
    __shared__ float sc[4];
    const int t = threadIdx.x;
    const float f = 0.5f * (ws[WS_COLSUM1 + t] * (1.0f / N1) +
                            ws[WS_COLSUM2 + t] * (1.0f / N2));
    const float fs = block_sum256(f * f, red, t);
    const float rsqf = rsqrtf(fs + 1e-8f);
    for (int e = 0; e < 4; ++e) {
        const float sv = sim[e * DIM + t];
        const float n2 = block_sum256(sv * sv, red, t);
        const float dt = block_sum256(sv * f, red, t);
        if (t == 0) sc[e] = dt * rsqf * rsqrtf(n2 + 1e-8f);
    }
    __syncthreads();
    if (t == 0) {
        float a = -1e30f, b = -1e30f;
        #pragma unroll
        for (int e = 0; e < 4; ++e) {
            const float v = sc[e];
            if (v > a) { b = a; a = v; } else if (v > b) { b = v; }
        }
        float w[4]; int ns = 0;
        #pragma unroll
        for (int e = 0; e < 4; ++e) {
            const bool keep = (sc[e] >= b) && (sc[e] > gates[e]);
            w[e] = keep ? sc[e] : 0.f;
            if (w[e] > 0.f) ns++;
        }
        if (ns < 1) ns = 1;
        ws[WS_GATE + 0] = w[0]; ws[WS_GATE + 1] = w[1];
        ws[WS_GATE + 2] = w[2]; ws[WS_GATE + 3] = w[3];
        ws[WS_GATE + 4] = 1.0f / (float)ns;
        ws[WS_GATE + 5] = w[0] + w[2] + w[3];
    }
    __syncthreads();
    float mx = -1e30f;
    for (int i = t; i < N2; i += 256) mx = fmaxf(mx, ws[WS_ALOGIT + i]);
    mx = block_max256(mx, red, t);
    float sm = 0.f;
    for (int i = t; i < N2; i += 256) {
        const float e_ = expf(ws[WS_ALOGIT + i] - mx);
        ws[WS_AW + i] = e_;
        sm += e_;
    }
    sm = block_sum256(sm, red, t);
    const float is = 1.0f / sm;
    for (int i = t; i < N2; i += 256) ws[WS_AW + i] *= is;
}

// ---------------- pooled = a^T x2 ----------------
__global__ __launch_bounds__(256) void k_pooled(const float* __restrict__ x2,
                                                float* __restrict__ ws)
{
    const int t = threadIdx.x;
    const int rbase = blockIdx.x * 64;
    float acc = 0.f;
    for (int r = 0; r < 64; ++r)
        acc = fmaf(ws[WS_AW + rbase + r], x2[(size_t)(rbase + r) * DIM + t], acc);
    atomicAdd(&ws[WS_POOLED + t], acc);
}

// ---------------- cvec = w1*s2mean + w2*(pooled@wf) ----------------
__global__ __launch_bounds__(256) void k_cvec(const float* __restrict__ wf,
                                              float* __restrict__ ws)
{
    __shared__ float pl[256];
    const int t = threadIdx.x;
    pl[t] = ws[WS_POOLED + t];
    __syncthreads();
    float acc = 0.f;
    for (int k = 0; k < 256; ++k) acc = fmaf(pl[k], wf[k * DIM + t], acc);
    const float w1 = ws[WS_GATE + 1], w2 = ws[WS_GATE + 2];
    ws[WS_CVEC + t] = w1 * (ws[WS_S2SUM + t] * (1.0f / N2)) + w2 * acc;
}

// ---------------- MFMA flash attention + fused epilogue ----------------
// 512 threads (8 waves, 2/SIMD), TQ=64, TK=128, phase-shifted staging.
// Accumulator chains split 2-way for MFMA-pipe ILP.
__global__ __launch_bounds__(512, 2) void k_flash(
    const float* __restrict__ x1, const float* __restrict__ b1,
    const float* __restrict__ wsf, float* __restrict__ out)
{
    extern __shared__ char sm[];
    const int t = threadIdx.x;
    const int w = t >> 6;
    const int lane = t & 63;
    const int l31 = lane & 31;
    const int lh = lane >> 5;
    const int qb = blockIdx.x * 64;
    const int kh = w >> 1, qh = w & 1;     // S-phase roles
    const int qp = w & 1, dpair = w >> 1;  // PV-phase roles
    const char* wsb = (const char*)wsf;
    const char* kpk = wsb + (size_t)WS_KPK * 4;
    const char* vpk = wsb + (size_t)WS_VPK * 4;
    const char* wqt = wsb + (size_t)WS_WQT * 4;
    const char* wot = wsb + (size_t)WS_WOT * 4;
    const char* w1t = wsb + (size_t)WS_W1T * 4;

    auto stage64 = [&](const char* gbase, int ldsoff) {
        #pragma unroll
        for (int i = 0; i < 8; ++i) {
            const int c = w * 8 + i;
            __builtin_amdgcn_global_load_lds(
                (AS1C uint32*)(gbase + c * 1024 + lane * 16),
                (AS3 uint32*)(sm + ldsoff + c * 1024), 16, 0, 0);
        }
    };

    // ---- prologue: x1 frags + rms partials
    #pragma unroll
    for (int i = 0; i < 4; ++i) {
        const int c = t + 512 * i;
        const int q = c >> 5, d0 = (c & 31) * 8;
        const float4 a = *(const float4*)(x1 + (size_t)(qb + q) * DIM + d0);
        const float4 b = *(const float4*)(x1 + (size_t)(qb + q) * DIM + d0 + 4);
        float ss = a.x*a.x + a.y*a.y + a.z*a.z + a.w*a.w
                 + b.x*b.x + b.y*b.y + b.z*b.z + b.w*b.w;
        #pragma unroll
        for (int o = 16; o > 0; o >>= 1) ss += __shfl_down(ss, o, 32);
        if ((t & 31) == 0) *(float*)(sm + L_RRS + q * 4) = ss;
        u4v pk;
        pk.x = f2bf2(a.x, a.y); pk.y = f2bf2(a.z, a.w);
        pk.z = f2bf2(b.x, b.y); pk.w = f2bf2(b.z, b.w);
        *(u4v*)(sm + L_X1PK + ((q >> 5) * 16 + (d0 >> 4)) * 1024
                + ((q & 31) + 32 * ((d0 >> 3) & 1)) * 16) = pk;
    }
    __syncthreads();
    if (t < 64) {
        const float s2 = *(const float*)(sm + L_RRS + t * 4);
        *(float*)(sm + L_RR + t * 4) = rsqrtf(s2 * (1.0f / DIM) + 1e-6f);
    }
    // ---- Q^T = wq^T * x1^T -> QPAD [q][d] bf16
    #pragma unroll
    for (int i = 0; i < 2; ++i) {
        const int mt = w, qt = i;
        f16v qa = (f16v)0.0f;
        #pragma unroll
        for (int s = 0; s < 16; ++s) {
            const s8v a  = *(const s8v*)(wqt + (mt * 16 + s) * 1024 + lane * 16);
            const s8v bb = *(const s8v*)(sm + L_X1PK + (qt * 16 + s) * 1024 + lane * 16);
            qa = MFMA32(a, bb, qa);
        }
        const int q = qt * 32 + l31;
        #pragma unroll
        for (int g = 0; g < 4; ++g) {
            const int d0 = 32 * mt + 8 * g + 4 * lh;
            u2v pk;
            pk.x = f2bf2(qa[4 * g + 0], qa[4 * g + 1]);
            pk.y = f2bf2(qa[4 * g + 2], qa[4 * g + 3]);
            *(u2v*)(sm + L_QPAD + q * 520 + d0 * 2) = pk;
        }
    }
    __syncthreads();
    // ---- load Q B-frags (qh half) into regs
    s8v qf[16];
    {
        const char* qbase = sm + L_QPAD + (qh * 32 + l31) * 520 + lh * 16;
        #pragma unroll
        for (int s = 0; s < 16; ++s) {
            S8U u;
            u.h[0] = *(const s4v*)(qbase + s * 32);
            u.h[1] = *(const s4v*)(qbase + s * 32 + 8);
            qf[s] = u.v;
        }
    }
    stage64(kpk, L_K);
    __syncthreads();   // drain K(0); QPAD reads complete

    f16v oacc0a = (f16v)0.0f, oacc0b = (f16v)0.0f;
    f16v oacc1a = (f16v)0.0f, oacc1b = (f16v)0.0f;
    float lsum = 0.0f;

    // ---- main loop: 32 tiles of 128 keys
    for (int tile = 0; tile < 32; ++tile) {
        stage64(vpk + (size_t)tile * 65536, L_V);
        // S^T = K(kh quarter) * Q^T(qh half), 2 accumulator chains
        f16v sacc0 = (f16v)0.0f, sacc1 = (f16v)0.0f;
        #pragma unroll
        for (int s2 = 0; s2 < 8; ++s2) {
            const s8v a0 = *(const s8v*)(sm + L_K
                + ((kh >> 1) * 32 + 2 * (2 * s2) + (kh & 1)) * 1024 + lane * 16);
            const s8v a1 = *(const s8v*)(sm + L_K
                + ((kh >> 1) * 32 + 2 * (2 * s2 + 1) + (kh & 1)) * 1024 + lane * 16);
            sacc0 = MFMA32(a0, qf[2 * s2], sacc0);
            sacc1 = MFMA32(a1, qf[2 * s2 + 1], sacc1);
        }
        // exp (max-free), pack P -> LDS B-frags
        #pragma unroll
        for (int g = 0; g < 4; ++g) {
            const float p0 = __expf((sacc0[4 * g + 0] + sacc1[4 * g + 0]) * 0.0625f);
            const float p1 = __expf((sacc0[4 * g + 1] + sacc1[4 * g + 1]) * 0.0625f);
            const float p2 = __expf((sacc0[4 * g + 2] + sacc1[4 * g + 2]) * 0.0625f);
            const float p3 = __expf((sacc0[4 * g + 3] + sacc1[4 * g + 3]) * 0.0625f);
            lsum += (p0 + p1) + (p2 + p3);
            const int keyo = 32 * kh + 8 * g + 4 * lh;
            const int kc = keyo >> 4, ko = keyo & 15;
            u2v pk; pk.x = f2bf2(p0, p1); pk.y = f2bf2(p2, p3);
            *(u2v*)(sm + L_P + (qh * 8 + kc) * 1024
                    + (l31 + 32 * (ko >> 3)) * 16 + (ko & 7) * 2) = pk;
        }
        __syncthreads();   // barrier A: drains V(tile); P visible; K free
        if (tile < 31) stage64(kpk + (size_t)(tile + 1) * 65536, L_K);
        // O^T += V^T * P^T, 2 chains per d-chunk
        s8v pf[8];
        #pragma unroll
        for (int kc = 0; kc < 8; ++kc)
            pf[kc] = *(const s8v*)(sm + L_P + (qp * 8 + kc) * 1024 + lane * 16);
        #pragma unroll
        for (int kc = 0; kc < 4; ++kc) {
            const int sub = 0, k3 = kc;
            const s8v a0 = *(const s8v*)(sm + L_V + (sub + 4 * (2 * dpair) + k3) * 1024 + lane * 16);
            const s8v a1 = *(const s8v*)(sm + L_V + (sub + 4 * (2 * dpair + 1) + k3) * 1024 + lane * 16);
            oacc0a = MFMA32(a0, pf[kc], oacc0a);
            oacc1a = MFMA32(a1, pf[kc], oacc1a);
        }
        #pragma unroll
        for (int kc = 4; kc < 8; ++kc) {
            const int sub = 32, k3 = kc & 3;
            const s8v a0 = *(const s8v*)(sm + L_V + (sub + 4 * (2 * dpair) + k3) * 1024 + lane * 16);
            const s8v a1 = *(const s8v*)(sm + L_V + (sub + 4 * (2 * dpair + 1) + k3) * 1024 + lane * 16);
            oacc0b = MFMA32(a0, pf[kc], oacc0b);
            oacc1b = MFMA32(a1, pf[kc], oacc1b);
        }
        __syncthreads();   // barrier B: drains K(tile+1); V/P free
    }

    // ---- softmax denominators
    *(float*)(sm + L_LP + ((w * 2 + lh) * 32 + l31) * 4) = lsum;
    __syncthreads();
    if (t < 64) {
        const int qh_ = t >> 5, c = t & 31;
        const float* lp = (const float*)(sm + L_LP);
        float l = 0.f;
        #pragma unroll
        for (int k2 = 0; k2 < 4; ++k2)
            l += lp[((k2 * 2 + qh_) * 2 + 0) * 32 + c]
               + lp[((k2 * 2 + qh_) * 2 + 1) * 32 + c];
        *(float*)(sm + L_LINV + t * 4) = 1.0f / l;
    }
    __syncthreads();
    // ---- pack Ohat = O/l into OBUF B-frags
    {
        const float li = *(const float*)(sm + L_LINV + (qp * 32 + l31) * 4);
        #pragma unroll
        for (int half = 0; half < 2; ++half) {
            const f16v accA = half ? oacc1a : oacc0a;
            const f16v accB = half ? oacc1b : oacc0b;
            const int dc = 2 * dpair + half;
            #pragma unroll
            for (int g = 0; g < 4; ++g) {
                const int d0 = dc * 32 + 8 * g + 4 * lh;
                u2v pk;
                pk.x = f2bf2((accA[4 * g + 0] + accB[4 * g + 0]) * li,
                             (accA[4 * g + 1] + accB[4 * g + 1]) * li);
                pk.y = f2bf2((accA[4 * g + 2] + accB[4 * g + 2]) * li,
                             (accA[4 * g + 3] + accB[4 * g + 3]) * li);
                *(u2v*)(sm + L_OBUF + (qp * 16 + (d0 >> 4)) * 1024
                        + (l31 + 32 * ((d0 >> 3) & 1)) * 16 + (d0 & 7) * 2) = pk;
            }
        }
    }
    // ---- rebuild x1 frags (epilogue copy, V region)
    #pragma unroll
    for (int i = 0; i < 4; ++i) {
        const int c = t + 512 * i;
        const int q = c >> 5, d0 = (c & 31) * 8;
        const float4 a = *(const float4*)(x1 + (size_t)(qb + q) * DIM + d0);
        const float4 b = *(const float4*)(x1 + (size_t)(qb + q) * DIM + d0 + 4);
        u4v pk;
        pk.x = f2bf2(a.x, a.y); pk.y = f2bf2(a.z, a.w);
        pk.z = f2bf2(b.x, b.y); pk.w = f2bf2(b.z, b.w);
        *(u4v*)(sm + L_X1PK2 + ((q >> 5) * 16 + (d0 >> 4)) * 1024
                + ((q & 31) + 32 * ((d0 >> 3) & 1)) * 16) = pk;
    }
    __syncthreads();
    // ---- combine: E0c^T = wo^T*Ohat^T ; S1^T = W1g^T*x1^T ; write out
    const float gw0 = wsf[WS_GATE + 0], gw1 = wsf[WS_GATE + 1];
    const float ginv = wsf[WS_GATE + 4], gcx1 = wsf[WS_GATE + 5];
    #pragma unroll
    for (int i = 0; i < 2; ++i) {
        const int mt = w, qt = i;
        f16v ea = (f16v)0.0f, sa = (f16v)0.0f;
        for (int s = 0; s < 16; ++s) {
            const s8v awo = *(const s8v*)(wot + (mt * 16 + s) * 1024 + lane * 16);
            const s8v aw1 = *(const s8v*)(w1t + (mt * 16 + s) * 1024 + lane * 16);
            const s8v bo = *(const s8v*)(sm + L_OBUF + (qt * 16 + s) * 1024 + lane * 16);
            const s8v bx = *(const s8v*)(sm + L_X1PK2 + (qt * 16 + s) * 1024 + lane * 16);
            ea = MFMA32(awo, bo, ea);
            sa = MFMA32(aw1, bx, sa);
        }
        const int q = qt * 32 + l31;
        const float rrq = *(const float*)(sm + L_RR + q * 4);
        #pragma unroll
        for (int g = 0; g < 4; ++g) {
            const int d0 = 32 * mt + 8 * g + 4 * lh;
            const float4 cv = *(const float4*)(wsf + WS_CVEC + d0);
            const float4 bb = *(const float4*)(b1 + d0);
            const float4 xx = *(const float4*)(x1 + (size_t)(qb + q) * DIM + d0);
            float ev0 = sa[4 * g + 0] * rrq + bb.x; ev0 = (ev0 > 0.f) ? ev0 : expm1f(ev0);
            float ev1 = sa[4 * g + 1] * rrq + bb.y; ev1 = (ev1 > 0.f) ? ev1 : expm1f(ev1);
            float ev2 = sa[4 * g + 2] * rrq + bb.z; ev2 = (ev2 > 0.f) ? ev2 : expm1f(ev2);
            float ev3 = sa[4 * g + 3] * rrq + bb.w; ev3 = (ev3 > 0.f) ? ev3 : expm1f(ev3);
            float4 o;
            o.x = ginv * (gcx1 * xx.x + gw0 * ea[4 * g + 0] + gw1 * ev0 + cv.x);
            o.y = ginv * (gcx1 * xx.y + gw0 * ea[4 * g + 1] + gw1 * ev1 + cv.y);
            o.z = ginv * (gcx1 * xx.z + gw0 * ea[4 * g + 2] + gw1 * ev2 + cv.z);
            o.w = ginv * (gcx1 * xx.w + gw0 * ea[4 * g + 3] + gw1 * ev3 + cv.w);
            *(float4*)(out + (size_t)(qb + q) * DIM + d0) = o;
        }
    }
}

extern "C" void kernel_launch(void* const* d_in, const int* in_sizes, int n_in,
                              void* d_out, int out_size, void* d_ws, size_t ws_size,
                              hipStream_t stream)
{
    (void)in_sizes; (void)n_in; (void)out_size; (void)ws_size;
    const float* x1    = (const float*)d_in[0];
    const float* x2    = (const float*)d_in[1];
    const float* sim   = (const float*)d_in[2];
    const float* gates = (const float*)d_in[3];
    const float* g1    = (const float*)d_in[4];
    const float* g2    = (const float*)d_in[5];
    const float* w1m   = (const float*)d_in[6];
    const float* b1    = (const float*)d_in[7];
    const float* w2m   = (const float*)d_in[8];
    const float* b2    = (const float*)d_in[9];
    const float* wq    = (const float*)d_in[10];
    const float* wk    = (const float*)d_in[11];
    const float* wv    = (const float*)d_in[12];
    const float* wo    = (const float*)d_in[13];
    const float* va    = (const float*)d_in[14];
    const float* ua    = (const float*)d_in[15];
    const float* wa    = (const float*)d_in[16];
    const float* wf    = (const float*)d_in[17];
    float* ws  = (float*)d_ws;
    float* out = (float*)d_out;

    hipMemsetAsync(ws + WS_ACC, 0, 1024 * sizeof(float), stream);
    hipLaunchKernelGGL(k_colsum12, dim3(320), dim3(256), 0, stream, x1, x2, ws);
    hipLaunchKernelGGL(k_wpack, dim3(224), dim3(256), 0, stream,
                       wq, wo, w1m, wk, wv, w2m, va, ua, g1, g2, ws);
    hipLaunchKernelGGL(k_x2prep2, dim3(N2 / 32), dim3(512), 0, stream, x2, b2, wa, ws);
    hipLaunchKernelGGL(k_gate, dim3(1), dim3(256), 0, stream, sim, gates, ws);
    hipLaunchKernelGGL(k_pooled, dim3(N2 / 64), dim3(256), 0, stream, x2, ws);
    hipLaunchKernelGGL(k_cvec, dim3(1), dim3(256), 0, stream, wf, ws);
    hipLaunchKernelGGL(k_flash, dim3(N1 / 64), dim3(512), SMEM_BYTES, stream,
                       x1, b1, ws, out);
}